// Round 2
// baseline (2324.578 us; speedup 1.0000x reference)
//
#include <hip/hip_runtime.h>
#include <math.h>

#define N_NODES 20000
#define E_HALF  160000
#define E_DIR   320000
#define IN_C    512
#define HID     128
#define OUTC    40

typedef unsigned short u16;
typedef unsigned int   u32;

// f32 weight arena offsets (elements)
#define OFF_WIN1  0
#define OFF_BIN1  32768
#define OFF_WIN2  32832
#define OFF_BIN2  41024
#define OFF_WMAP1 41152
#define OFF_BMAP1 57536
#define OFF_WMAP2 57600
#define OFF_BMAP2 57856
#define OFF_WOUT1 57860
#define OFF_BOUT1 66052
#define OFF_WOUT2 66116
#define OFF_BOUT2 68676
#define OFF_W1_0  68716
#define OFF_W2_0  68720
#define OFF_W1_1  72816
#define OFF_W2_1  72820
#define WTOTAL    76916

__device__ __forceinline__ float bfu2f(u16 u) {
  union { u32 i; float f; } v; v.i = ((u32)u) << 16; return v.f;
}
__device__ __forceinline__ void unpack8(const uint4 c, float* f) {
  union { u32 i; float x; } v;
  v.i = c.x << 16;          f[0] = v.x;
  v.i = c.x & 0xffff0000u;  f[1] = v.x;
  v.i = c.y << 16;          f[2] = v.x;
  v.i = c.y & 0xffff0000u;  f[3] = v.x;
  v.i = c.z << 16;          f[4] = v.x;
  v.i = c.z & 0xffff0000u;  f[5] = v.x;
  v.i = c.w << 16;          f[6] = v.x;
  v.i = c.w & 0xffff0000u;  f[7] = v.x;
}
__device__ __forceinline__ u16 f2bf(float f) {
  union { float f; u32 u; } v; v.f = f;
  u32 u = v.u;
  u += 0x7fffu + ((u >> 16) & 1u);   // RNE
  return (u16)(u >> 16);
}

// ---- K0: sniff input float dtype. flag=1 -> bf16, flag=0 -> f32 ------------
__global__ void k_sniff(const u16* __restrict__ xv, int* __restrict__ flag) {
  __shared__ int s_bad;
  if (threadIdx.x == 0) s_bad = 0;
  __syncthreads();
  int bad = 0;
  for (int i = threadIdx.x; i < 2048; i += 256) {
    u16 u = xv[i];
    u32 ex = (u >> 7) & 0xFFu;
    if (!(ex >= 100 && ex <= 140) && (u & 0x7FFFu) != 0) bad++;
  }
  atomicAdd(&s_bad, bad);
  __syncthreads();
  if (threadIdx.x == 0) *flag = (s_bad < 64) ? 1 : 0;
}

// ---- K0b: convert all weights into an f32 arena ----------------------------
struct P16 { const void* p[16]; };
__global__ __launch_bounds__(256) void k_convert(P16 s, const int* __restrict__ flag,
                                                 float* __restrict__ dst) {
  const int offs[17] = {OFF_WIN1, OFF_BIN1, OFF_WIN2, OFF_BIN2, OFF_WMAP1,
                        OFF_BMAP1, OFF_WMAP2, OFF_BMAP2, OFF_WOUT1, OFF_BOUT1,
                        OFF_WOUT2, OFF_BOUT2, OFF_W1_0, OFF_W2_0, OFF_W1_1,
                        OFF_W2_1, WTOTAL};
  const int i = blockIdx.x * 256 + threadIdx.x;
  if (i >= WTOTAL) return;
  int sg = 0;
  #pragma unroll
  for (int k = 1; k < 16; ++k) if (i >= offs[k]) sg = k;
  const int j = i - offs[sg];
  float v;
  if (*flag) v = bfu2f(((const u16*)s.p[sg])[j]);
  else       v = ((const float*)s.p[sg])[j];
  dst[i] = v;
}

// ---- K1: h = MLP_in(x)  [N,512] -> relu 64 -> [N,128] ----------------------
__global__ __launch_bounds__(256) void k_mlp_in(
    const void* __restrict__ xv, const int* __restrict__ flag,
    const float* __restrict__ wf, float* __restrict__ h)
{
  __shared__ float s_hid[4][68];
  const int t = threadIdx.x;
  const int n0 = blockIdx.x * 4;
  const int bf = *flag;
  {
    const int n = t >> 6, j = t & 63;
    const int node = n0 + n;
    float acc = wf[OFF_BIN1 + j];
    const float* wr = wf + OFF_WIN1 + j * IN_C;
    if (bf) {
      const u16* xr = (const u16*)xv + node * IN_C;
      for (int kk = 0; kk < IN_C; kk += 8) {
        uint4 xc = *(const uint4*)(xr + kk);
        float xf[8]; unpack8(xc, xf);
        float4 wa = *(const float4*)(wr + kk);
        float4 wb = *(const float4*)(wr + kk + 4);
        acc += xf[0]*wa.x + xf[1]*wa.y + xf[2]*wa.z + xf[3]*wa.w
             + xf[4]*wb.x + xf[5]*wb.y + xf[6]*wb.z + xf[7]*wb.w;
      }
    } else {
      const float* xr = (const float*)xv + node * IN_C;
      for (int kk = 0; kk < IN_C; kk += 8) {
        float4 xa = *(const float4*)(xr + kk);
        float4 xb = *(const float4*)(xr + kk + 4);
        float4 wa = *(const float4*)(wr + kk);
        float4 wb = *(const float4*)(wr + kk + 4);
        acc += xa.x*wa.x + xa.y*wa.y + xa.z*wa.z + xa.w*wa.w
             + xb.x*wb.x + xb.y*wb.y + xb.z*wb.z + xb.w*wb.w;
      }
    }
    s_hid[n][j] = fmaxf(acc, 0.f);
  }
  __syncthreads();
  #pragma unroll
  for (int rep = 0; rep < 2; ++rep) {
    const int flat = t + rep * 256;
    const int n = flat >> 7, o = flat & 127;
    float acc = wf[OFF_BIN2 + o];
    const float* wr = wf + OFF_WIN2 + o * 64;
    #pragma unroll
    for (int kk = 0; kk < 64; kk += 4) {
      float4 wv = *(const float4*)(wr + kk);
      acc += s_hid[n][kk]*wv.x + s_hid[n][kk+1]*wv.y
           + s_hid[n][kk+2]*wv.z + s_hid[n][kk+3]*wv.w;
    }
    h[(n0 + n) * HID + o] = acc;
  }
}

// ---- K2: edge restriction maps  [E,256] -> relu 64 -> 4 --------------------
__global__ __launch_bounds__(256) void k_edge_maps(
    const float* __restrict__ h, const int* __restrict__ ei,
    const float* __restrict__ wf, float* __restrict__ maps)
{
  __shared__ float s_u[16][68];
  const int t = threadIdx.x;
  const int e0 = blockIdx.x * 16;
  const int el = t & 15, jg = t >> 4;
  const int e = e0 + el;
  const int sn = ei[e], dn = ei[E_DIR + e];
  const int j0 = jg * 4;
  float a0 = wf[OFF_BMAP1 + j0 + 0];
  float a1 = wf[OFF_BMAP1 + j0 + 1];
  float a2 = wf[OFF_BMAP1 + j0 + 2];
  float a3 = wf[OFF_BMAP1 + j0 + 3];
  const float* hs = h + sn * HID;
  const float* hd = h + dn * HID;
  const float* w0 = wf + OFF_WMAP1 + (j0 + 0) * 256;
  const float* w1 = wf + OFF_WMAP1 + (j0 + 1) * 256;
  const float* w2 = wf + OFF_WMAP1 + (j0 + 2) * 256;
  const float* w3 = wf + OFF_WMAP1 + (j0 + 3) * 256;
  for (int kk = 0; kk < 256; kk += 4) {
    const float* eb = (kk < 128) ? (hs + kk) : (hd + kk - 128);
    float4 ev = *(const float4*)eb;
    float4 v0 = *(const float4*)(w0 + kk);
    float4 v1 = *(const float4*)(w1 + kk);
    float4 v2 = *(const float4*)(w2 + kk);
    float4 v3 = *(const float4*)(w3 + kk);
    a0 += ev.x*v0.x + ev.y*v0.y + ev.z*v0.z + ev.w*v0.w;
    a1 += ev.x*v1.x + ev.y*v1.y + ev.z*v1.z + ev.w*v1.w;
    a2 += ev.x*v2.x + ev.y*v2.y + ev.z*v2.z + ev.w*v2.w;
    a3 += ev.x*v3.x + ev.y*v3.y + ev.z*v3.z + ev.w*v3.w;
  }
  s_u[el][j0+0] = fmaxf(a0, 0.f);
  s_u[el][j0+1] = fmaxf(a1, 0.f);
  s_u[el][j0+2] = fmaxf(a2, 0.f);
  s_u[el][j0+3] = fmaxf(a3, 0.f);
  __syncthreads();
  if (t < 64) {
    const int ee = t >> 2, ko = t & 3;
    float acc = wf[OFF_BMAP2 + ko];
    const float* wr = wf + OFF_WMAP2 + ko * 64;
    #pragma unroll
    for (int j = 0; j < 64; j += 4) {
      float4 wv = *(const float4*)(wr + j);
      acc += s_u[ee][j]*wv.x + s_u[ee][j+1]*wv.y
           + s_u[ee][j+2]*wv.z + s_u[ee][j+3]*wv.w;
    }
    maps[(e0 + ee) * 4 + ko] = acc;
  }
}

// ---- K3: diag[n] += F_e^T F_e over out-edges -------------------------------
__global__ __launch_bounds__(256) void k_ftf_diag(
    const float* __restrict__ maps, const int* __restrict__ ei,
    float* __restrict__ diag)
{
  const int e = blockIdx.x * 256 + threadIdx.x;
  if (e >= E_DIR) return;
  float4 m = *(const float4*)(maps + e * 4);   // [m00,m01,m10,m11]
  float f00 = m.x * m.x + m.z * m.z;
  float f01 = m.x * m.y + m.z * m.w;
  float f11 = m.y * m.y + m.w * m.w;
  const int sn = ei[e];
  atomicAdd(&diag[sn * 4 + 0], f00);
  atomicAdd(&diag[sn * 4 + 1], f01);
  atomicAdd(&diag[sn * 4 + 3], f11);
}

// ---- K4: Dinv = diag^{-1/2} (2x2 sym eig, clip 1e-6), diag_n ---------------
__global__ void k_norm(const float* __restrict__ diag, float* __restrict__ Dinv,
                       float* __restrict__ diag_n)
{
  const int n = blockIdx.x * 256 + threadIdx.x;
  if (n >= N_NODES) return;
  float a = diag[n * 4 + 0], b = diag[n * 4 + 1], c = diag[n * 4 + 3];
  float mean = 0.5f * (a + c), diff = 0.5f * (a - c);
  float rad = sqrtf(diff * diff + b * b);
  float l1 = mean - rad, l2 = mean + rad;
  float s1 = 1.0f / sqrtf(fmaxf(l1, 1e-6f));
  float s2 = 1.0f / sqrtf(fmaxf(l2, 1e-6f));
  float D00, D01, D11;
  if (rad < 1e-20f) {
    float s = 1.0f / sqrtf(fmaxf(mean, 1e-6f));
    D00 = s; D01 = 0.f; D11 = s;
  } else {
    float vx, vy;
    if (diff >= 0.f) { vx = rad + diff; vy = b; }
    else             { vx = b;          vy = rad - diff; }
    float inv = 1.0f / sqrtf(vx * vx + vy * vy);
    float ux = vx * inv, uy = vy * inv;     // eigvec of l2
    D00 = s1 * uy * uy + s2 * ux * ux;
    D01 = (s2 - s1) * ux * uy;
    D11 = s1 * ux * ux + s2 * uy * uy;
  }
  Dinv[n * 4 + 0] = D00; Dinv[n * 4 + 1] = D01;
  Dinv[n * 4 + 2] = D01; Dinv[n * 4 + 3] = D11;
  float t00 = D00 * a + D01 * b, t01 = D00 * b + D01 * c;
  float t10 = D01 * a + D11 * b, t11 = D01 * b + D11 * c;
  diag_n[n * 4 + 0] = t00 * D00 + t01 * D01;
  diag_n[n * 4 + 1] = t00 * D01 + t01 * D11;
  diag_n[n * 4 + 2] = t10 * D00 + t11 * D01;
  diag_n[n * 4 + 3] = t10 * D01 + t11 * D11;
}

// ---- K5: off_n = Dinv[src] * (-(F_e^T F_rev)) * Dinv[dst] ------------------
__global__ void k_offn(const float* __restrict__ maps, const int* __restrict__ ei,
                       const float* __restrict__ Dinv, float* __restrict__ off_n)
{
  const int e = blockIdx.x * 256 + threadIdx.x;
  if (e >= E_DIR) return;
  const int r = (e < E_HALF) ? (e + E_HALF) : (e - E_HALF);
  float4 me = *(const float4*)(maps + e * 4);
  float4 mr = *(const float4*)(maps + r * 4);
  float o00 = -(me.x * mr.x + me.z * mr.z);
  float o01 = -(me.x * mr.y + me.z * mr.w);
  float o10 = -(me.y * mr.x + me.w * mr.z);
  float o11 = -(me.y * mr.y + me.w * mr.w);
  const int sn = ei[e], dn = ei[E_DIR + e];
  float4 Ds = *(const float4*)(Dinv + sn * 4);
  float4 Dd = *(const float4*)(Dinv + dn * 4);
  float t00 = Ds.x * o00 + Ds.y * o10;
  float t01 = Ds.x * o01 + Ds.y * o11;
  float t10 = Ds.z * o00 + Ds.w * o10;
  float t11 = Ds.z * o01 + Ds.w * o11;
  float4 q;
  q.x = t00 * Dd.x + t01 * Dd.z;
  q.y = t00 * Dd.y + t01 * Dd.w;
  q.z = t10 * Dd.x + t11 * Dd.z;
  q.w = t10 * Dd.y + t11 * Dd.w;
  *(float4*)(off_n + e * 4) = q;
}

// ---- K6a: Ht = W1^T (h3 @ W2^T) per node -----------------------------------
__global__ __launch_bounds__(256) void k_ht(
    const float* __restrict__ h, const float* __restrict__ wf,
    int offW1, int offW2, float* __restrict__ Ht)
{
  const int t = threadIdx.x;
  const int n = blockIdx.x * 4 + (t >> 6);
  const int g = t & 63;
  const float w1_00 = wf[offW1 + 0], w1_01 = wf[offW1 + 1];
  const float w1_10 = wf[offW1 + 2], w1_11 = wf[offW1 + 3];
  float acc0 = 0.f, acc1 = 0.f;
  const float* wr = wf + offW2 + g * 64;
  const float* h0 = h + n * HID;
  for (int kk = 0; kk < 64; kk += 4) {
    float4 wv = *(const float4*)(wr + kk);
    float4 p0 = *(const float4*)(h0 + kk);
    float4 p1 = *(const float4*)(h0 + 64 + kk);
    acc0 += p0.x*wv.x + p0.y*wv.y + p0.z*wv.z + p0.w*wv.w;
    acc1 += p1.x*wv.x + p1.y*wv.y + p1.z*wv.z + p1.w*wv.w;
  }
  Ht[n * HID + g]      = w1_00 * acc0 + w1_10 * acc1;
  Ht[n * HID + 64 + g] = w1_01 * acc0 + w1_11 * acc1;
}

// ---- K6b: acc[src] += off_n[e] @ Ht[dst] -----------------------------------
__global__ __launch_bounds__(256) void k_msgs(
    const float* __restrict__ off_n, const int* __restrict__ ei,
    const float* __restrict__ Ht, float* __restrict__ acc)
{
  const int t = threadIdx.x;
  const int e = blockIdx.x * 4 + (t >> 6);
  const int g = t & 63;
  float4 o = *(const float4*)(off_n + e * 4);
  const int sn = ei[e], dn = ei[E_DIR + e];
  float ht0 = Ht[dn * HID + g], ht1 = Ht[dn * HID + 64 + g];
  atomicAdd(&acc[sn * HID + g],      o.x * ht0 + o.y * ht1);
  atomicAdd(&acc[sn * HID + 64 + g], o.z * ht0 + o.w * ht1);
}

// ---- K6c: h3 -= elu(diag_n @ Ht + acc) -------------------------------------
__global__ __launch_bounds__(256) void k_update(
    const float* __restrict__ diag_n, const float* __restrict__ Ht,
    const float* __restrict__ acc, float* h)
{
  const int i = blockIdx.x * 256 + threadIdx.x;   // over N*128
  const int n = i >> 7, r = i & 127, ii = r >> 6, g = r & 63;
  float4 dn = *(const float4*)(diag_n + n * 4);
  float ht0 = Ht[n * HID + g], ht1 = Ht[n * HID + 64 + g];
  float lh = (ii == 0) ? (dn.x * ht0 + dn.y * ht1) : (dn.z * ht0 + dn.w * ht1);
  lh += acc[i];
  float e = (lh > 0.f) ? lh : (expf(lh) - 1.f);
  h[i] = h[i] - e;
}

// ---- K7: out = MLP_out(h3) [N,128] -> relu 64 -> 40 ------------------------
__global__ __launch_bounds__(256) void k_mlp_out(
    const float* __restrict__ h, const float* __restrict__ wf,
    const int* __restrict__ flag, void* __restrict__ outv)
{
  __shared__ float s_hid[4][68];
  const int t = threadIdx.x;
  const int n0 = blockIdx.x * 4;
  {
    const int n = t >> 6, j = t & 63;
    float acc = wf[OFF_BOUT1 + j];
    const float* hr = h + (n0 + n) * HID;
    const float* wr = wf + OFF_WOUT1 + j * HID;
    for (int kk = 0; kk < HID; kk += 4) {
      float4 wv = *(const float4*)(wr + kk);
      float4 hv = *(const float4*)(hr + kk);
      acc += hv.x*wv.x + hv.y*wv.y + hv.z*wv.z + hv.w*wv.w;
    }
    s_hid[n][j] = fmaxf(acc, 0.f);
  }
  __syncthreads();
  if (t < 160) {
    const int n = t / 40, o = t % 40;
    float acc = wf[OFF_BOUT2 + o];
    const float* wr = wf + OFF_WOUT2 + o * 64;
    #pragma unroll
    for (int j = 0; j < 64; j += 4) {
      float4 wv = *(const float4*)(wr + j);
      acc += s_hid[n][j]*wv.x + s_hid[n][j+1]*wv.y
           + s_hid[n][j+2]*wv.z + s_hid[n][j+3]*wv.w;
    }
    const int idx = (n0 + n) * OUTC + o;
    if (*flag) ((u16*)outv)[idx] = f2bf(acc);
    else       ((float*)outv)[idx] = acc;
  }
}

extern "C" void kernel_launch(void* const* d_in, const int* in_sizes, int n_in,
                              void* d_out, int out_size, void* d_ws, size_t ws_size,
                              hipStream_t stream)
{
  const int* ei = (const int*)d_in[1];

  float* ws   = (float*)d_ws;
  float* wf   = ws;                               // [0, 76928)
  int*   flag = (int*)(ws + 76928);
  float* h      = ws + 76944;                     // 2,560,000
  float* Ht     = h + 2560000;                    // 2,560,000
  float* off_n  = Ht + 2560000;                   // 1,280,000
  float* diag   = off_n + 1280000;                // 80,000
  float* Dinv   = diag + 80000;                   // 80,000
  float* diag_n = Dinv + 80000;                   // 80,000
  float* X      = diag_n + 80000;                 // 2,560,000 (maps, then acc)
  float* maps   = X;
  float* acc    = X;

  P16 P;
  for (int i = 0; i < 16; ++i) P.p[i] = d_in[2 + i];

  k_sniff<<<1, 256, 0, stream>>>((const u16*)d_in[0], flag);
  k_convert<<<(WTOTAL + 255) / 256, 256, 0, stream>>>(P, flag, wf);
  hipMemsetAsync(diag, 0, 80000 * sizeof(float), stream);
  k_mlp_in<<<N_NODES / 4, 256, 0, stream>>>(d_in[0], flag, wf, h);
  k_edge_maps<<<E_DIR / 16, 256, 0, stream>>>(h, ei, wf, maps);
  k_ftf_diag<<<E_DIR / 256, 256, 0, stream>>>(maps, ei, diag);
  k_norm<<<(N_NODES + 255) / 256, 256, 0, stream>>>(diag, Dinv, diag_n);
  k_offn<<<E_DIR / 256, 256, 0, stream>>>(maps, ei, Dinv, off_n);

  const int offW1s[2] = {OFF_W1_0, OFF_W1_1};
  const int offW2s[2] = {OFF_W2_0, OFF_W2_1};
  for (int l = 0; l < 2; ++l) {
    k_ht<<<N_NODES / 4, 256, 0, stream>>>(h, wf, offW1s[l], offW2s[l], Ht);
    hipMemsetAsync(acc, 0, 2560000 * sizeof(float), stream);
    k_msgs<<<E_DIR / 4, 256, 0, stream>>>(off_n, ei, Ht, acc);
    k_update<<<N_NODES * HID / 256, 256, 0, stream>>>(diag_n, Ht, acc, h);
  }
  k_mlp_out<<<N_NODES / 4, 256, 0, stream>>>(h, wf, flag, d_out);
}

// Round 3
// 1399.524 us; speedup vs baseline: 1.6610x; 1.6610x over previous
//
#include <hip/hip_runtime.h>
#include <math.h>

#define N_NODES 20000
#define E_HALF  160000
#define E_DIR   320000
#define IN_C    512
#define HID     128
#define OUTC    40

typedef unsigned short u16;
typedef unsigned int   u32;

// f32 weight arena offsets (elements)
#define OFF_WIN1  0
#define OFF_BIN1  32768
#define OFF_WIN2  32832
#define OFF_BIN2  41024
#define OFF_WMAP1 41152
#define OFF_BMAP1 57536
#define OFF_WMAP2 57600
#define OFF_BMAP2 57856
#define OFF_WOUT1 57860
#define OFF_BOUT1 66052
#define OFF_WOUT2 66116
#define OFF_BOUT2 68676
#define OFF_W1_0  68716
#define OFF_W2_0  68720
#define OFF_W1_1  72816
#define OFF_W2_1  72820
#define WTOTAL    76916

__device__ __forceinline__ float bfu2f(u16 u) {
  union { u32 i; float f; } v; v.i = ((u32)u) << 16; return v.f;
}
__device__ __forceinline__ void unpack8(const uint4 c, float* f) {
  union { u32 i; float x; } v;
  v.i = c.x << 16;          f[0] = v.x;
  v.i = c.x & 0xffff0000u;  f[1] = v.x;
  v.i = c.y << 16;          f[2] = v.x;
  v.i = c.y & 0xffff0000u;  f[3] = v.x;
  v.i = c.z << 16;          f[4] = v.x;
  v.i = c.z & 0xffff0000u;  f[5] = v.x;
  v.i = c.w << 16;          f[6] = v.x;
  v.i = c.w & 0xffff0000u;  f[7] = v.x;
}
__device__ __forceinline__ u16 f2bf(float f) {
  union { float f; u32 u; } v; v.f = f;
  u32 u = v.u;
  u += 0x7fffu + ((u >> 16) & 1u);   // RNE
  return (u16)(u >> 16);
}

// ---- K0: sniff input float dtype. flag=1 -> bf16, flag=0 -> f32 ------------
__global__ void k_sniff(const u16* __restrict__ xv, int* __restrict__ flag) {
  __shared__ int s_bad;
  if (threadIdx.x == 0) s_bad = 0;
  __syncthreads();
  int bad = 0;
  for (int i = threadIdx.x; i < 2048; i += 256) {
    u16 u = xv[i];
    u32 ex = (u >> 7) & 0xFFu;
    if (!(ex >= 100 && ex <= 140) && (u & 0x7FFFu) != 0) bad++;
  }
  atomicAdd(&s_bad, bad);
  __syncthreads();
  if (threadIdx.x == 0) *flag = (s_bad < 64) ? 1 : 0;
}

// ---- K0b: convert all weights into an f32 arena ----------------------------
struct P16 { const void* p[16]; };
__global__ __launch_bounds__(256) void k_convert(P16 s, const int* __restrict__ flag,
                                                 float* __restrict__ dst) {
  const int offs[17] = {OFF_WIN1, OFF_BIN1, OFF_WIN2, OFF_BIN2, OFF_WMAP1,
                        OFF_BMAP1, OFF_WMAP2, OFF_BMAP2, OFF_WOUT1, OFF_BOUT1,
                        OFF_WOUT2, OFF_BOUT2, OFF_W1_0, OFF_W2_0, OFF_W1_1,
                        OFF_W2_1, WTOTAL};
  const int i = blockIdx.x * 256 + threadIdx.x;
  if (i >= WTOTAL) return;
  int sg = 0;
  #pragma unroll
  for (int k = 1; k < 16; ++k) if (i >= offs[k]) sg = k;
  const int j = i - offs[sg];
  float v;
  if (*flag) v = bfu2f(((const u16*)s.p[sg])[j]);
  else       v = ((const float*)s.p[sg])[j];
  dst[i] = v;
}

// ---- K1: h = MLP_in(x)  [N,512] -> relu 64 -> [N,128] ----------------------
__global__ __launch_bounds__(256) void k_mlp_in(
    const void* __restrict__ xv, const int* __restrict__ flag,
    const float* __restrict__ wf, float* __restrict__ h)
{
  __shared__ float s_hid[4][68];
  const int t = threadIdx.x;
  const int n0 = blockIdx.x * 4;
  const int bf = *flag;
  {
    const int n = t >> 6, j = t & 63;
    const int node = n0 + n;
    float acc = wf[OFF_BIN1 + j];
    const float* wr = wf + OFF_WIN1 + j * IN_C;
    if (bf) {
      const u16* xr = (const u16*)xv + node * IN_C;
      for (int kk = 0; kk < IN_C; kk += 8) {
        uint4 xc = *(const uint4*)(xr + kk);
        float xf[8]; unpack8(xc, xf);
        float4 wa = *(const float4*)(wr + kk);
        float4 wb = *(const float4*)(wr + kk + 4);
        acc += xf[0]*wa.x + xf[1]*wa.y + xf[2]*wa.z + xf[3]*wa.w
             + xf[4]*wb.x + xf[5]*wb.y + xf[6]*wb.z + xf[7]*wb.w;
      }
    } else {
      const float* xr = (const float*)xv + node * IN_C;
      for (int kk = 0; kk < IN_C; kk += 8) {
        float4 xa = *(const float4*)(xr + kk);
        float4 xb = *(const float4*)(xr + kk + 4);
        float4 wa = *(const float4*)(wr + kk);
        float4 wb = *(const float4*)(wr + kk + 4);
        acc += xa.x*wa.x + xa.y*wa.y + xa.z*wa.z + xa.w*wa.w
             + xb.x*wb.x + xb.y*wb.y + xb.z*wb.z + xb.w*wb.w;
      }
    }
    s_hid[n][j] = fmaxf(acc, 0.f);
  }
  __syncthreads();
  #pragma unroll
  for (int rep = 0; rep < 2; ++rep) {
    const int flat = t + rep * 256;
    const int n = flat >> 7, o = flat & 127;
    float acc = wf[OFF_BIN2 + o];
    const float* wr = wf + OFF_WIN2 + o * 64;
    #pragma unroll
    for (int kk = 0; kk < 64; kk += 4) {
      float4 wv = *(const float4*)(wr + kk);
      acc += s_hid[n][kk]*wv.x + s_hid[n][kk+1]*wv.y
           + s_hid[n][kk+2]*wv.z + s_hid[n][kk+3]*wv.w;
    }
    h[(n0 + n) * HID + o] = acc;
  }
}

// ---- K1b: u_s = h @ W1a^T, u_d = h @ W1b^T  (linearity split of edge MLP) --
__global__ __launch_bounds__(256) void k_uproj(
    const float* __restrict__ h, const float* __restrict__ wf,
    float* __restrict__ u_s, float* __restrict__ u_d)
{
  const int t = threadIdx.x;
  const int n = blockIdx.x * 4 + (t >> 6);
  const int j = t & 63;
  float as = 0.f, ad = 0.f;
  const float* hr = h + n * HID;
  const float* ws = wf + OFF_WMAP1 + j * 256;       // cols 0..127  -> src half
  const float* wd = ws + 128;                        // cols 128..255 -> dst half
  #pragma unroll
  for (int kk = 0; kk < 128; kk += 4) {
    float4 hv = *(const float4*)(hr + kk);
    float4 s4 = *(const float4*)(ws + kk);
    float4 d4 = *(const float4*)(wd + kk);
    as += hv.x*s4.x + hv.y*s4.y + hv.z*s4.z + hv.w*s4.w;
    ad += hv.x*d4.x + hv.y*d4.y + hv.z*d4.z + hv.w*d4.w;
  }
  u_s[n * 64 + j] = as;
  u_d[n * 64 + j] = ad;
}

// ---- K2: edge maps from node projections -----------------------------------
// maps[e] = b2 + W2 @ relu(u_s[src] + u_d[dst] + b1)
__global__ __launch_bounds__(256) void k_edge_maps2(
    const float* __restrict__ u_s, const float* __restrict__ u_d,
    const int* __restrict__ ei, const float* __restrict__ wf,
    float* __restrict__ maps)
{
  __shared__ float s_act[64][68];
  const int t = threadIdx.x;
  const int w = t >> 6, l = t & 63;
  const int e0 = blockIdx.x * 64;
  const float bias = wf[OFF_BMAP1 + l];
  const int eb = e0 + w * 16;
  #pragma unroll 4
  for (int i = 0; i < 16; ++i) {
    const int e = eb + i;
    const int sn = ei[e], dn = ei[E_DIR + e];
    float v = u_s[sn * 64 + l] + u_d[dn * 64 + l] + bias;
    s_act[w * 16 + i][l] = fmaxf(v, 0.f);
  }
  __syncthreads();
  // 256 threads = 64 edges x 4 outputs
  const int ee = t >> 2, ko = t & 3;
  float acc = wf[OFF_BMAP2 + ko];
  const float* wr = wf + OFF_WMAP2 + ko * 64;
  #pragma unroll
  for (int j = 0; j < 64; j += 4) {
    float4 wv = *(const float4*)(wr + j);
    float4 av = *(const float4*)(&s_act[ee][j]);
    acc += av.x*wv.x + av.y*wv.y + av.z*wv.z + av.w*wv.w;
  }
  maps[(e0 + ee) * 4 + ko] = acc;
}

// ---- K3: diag[n] += F_e^T F_e over out-edges -------------------------------
__global__ __launch_bounds__(256) void k_ftf_diag(
    const float* __restrict__ maps, const int* __restrict__ ei,
    float* __restrict__ diag)
{
  const int e = blockIdx.x * 256 + threadIdx.x;
  if (e >= E_DIR) return;
  float4 m = *(const float4*)(maps + e * 4);   // [m00,m01,m10,m11]
  float f00 = m.x * m.x + m.z * m.z;
  float f01 = m.x * m.y + m.z * m.w;
  float f11 = m.y * m.y + m.w * m.w;
  const int sn = ei[e];
  atomicAdd(&diag[sn * 4 + 0], f00);
  atomicAdd(&diag[sn * 4 + 1], f01);
  atomicAdd(&diag[sn * 4 + 3], f11);
}

// ---- K4: Dinv = diag^{-1/2} (2x2 sym eig, clip 1e-6), diag_n ---------------
__global__ void k_norm(const float* __restrict__ diag, float* __restrict__ Dinv,
                       float* __restrict__ diag_n)
{
  const int n = blockIdx.x * 256 + threadIdx.x;
  if (n >= N_NODES) return;
  float a = diag[n * 4 + 0], b = diag[n * 4 + 1], c = diag[n * 4 + 3];
  float mean = 0.5f * (a + c), diff = 0.5f * (a - c);
  float rad = sqrtf(diff * diff + b * b);
  float l1 = mean - rad, l2 = mean + rad;
  float s1 = 1.0f / sqrtf(fmaxf(l1, 1e-6f));
  float s2 = 1.0f / sqrtf(fmaxf(l2, 1e-6f));
  float D00, D01, D11;
  if (rad < 1e-20f) {
    float s = 1.0f / sqrtf(fmaxf(mean, 1e-6f));
    D00 = s; D01 = 0.f; D11 = s;
  } else {
    float vx, vy;
    if (diff >= 0.f) { vx = rad + diff; vy = b; }
    else             { vx = b;          vy = rad - diff; }
    float inv = 1.0f / sqrtf(vx * vx + vy * vy);
    float ux = vx * inv, uy = vy * inv;     // eigvec of l2
    D00 = s1 * uy * uy + s2 * ux * ux;
    D01 = (s2 - s1) * ux * uy;
    D11 = s1 * ux * ux + s2 * uy * uy;
  }
  Dinv[n * 4 + 0] = D00; Dinv[n * 4 + 1] = D01;
  Dinv[n * 4 + 2] = D01; Dinv[n * 4 + 3] = D11;
  float t00 = D00 * a + D01 * b, t01 = D00 * b + D01 * c;
  float t10 = D01 * a + D11 * b, t11 = D01 * b + D11 * c;
  diag_n[n * 4 + 0] = t00 * D00 + t01 * D01;
  diag_n[n * 4 + 1] = t00 * D01 + t01 * D11;
  diag_n[n * 4 + 2] = t10 * D00 + t11 * D01;
  diag_n[n * 4 + 3] = t10 * D01 + t11 * D11;
}

// ---- K5: off_n = Dinv[src] * (-(F_e^T F_rev)) * Dinv[dst] ------------------
__global__ void k_offn(const float* __restrict__ maps, const int* __restrict__ ei,
                       const float* __restrict__ Dinv, float* __restrict__ off_n)
{
  const int e = blockIdx.x * 256 + threadIdx.x;
  if (e >= E_DIR) return;
  const int r = (e < E_HALF) ? (e + E_HALF) : (e - E_HALF);
  float4 me = *(const float4*)(maps + e * 4);
  float4 mr = *(const float4*)(maps + r * 4);
  float o00 = -(me.x * mr.x + me.z * mr.z);
  float o01 = -(me.x * mr.y + me.z * mr.w);
  float o10 = -(me.y * mr.x + me.w * mr.z);
  float o11 = -(me.y * mr.y + me.w * mr.w);
  const int sn = ei[e], dn = ei[E_DIR + e];
  float4 Ds = *(const float4*)(Dinv + sn * 4);
  float4 Dd = *(const float4*)(Dinv + dn * 4);
  float t00 = Ds.x * o00 + Ds.y * o10;
  float t01 = Ds.x * o01 + Ds.y * o11;
  float t10 = Ds.z * o00 + Ds.w * o10;
  float t11 = Ds.z * o01 + Ds.w * o11;
  float4 q;
  q.x = t00 * Dd.x + t01 * Dd.z;
  q.y = t00 * Dd.y + t01 * Dd.w;
  q.z = t10 * Dd.x + t11 * Dd.z;
  q.w = t10 * Dd.y + t11 * Dd.w;
  *(float4*)(off_n + e * 4) = q;
}

// ---- K6a: Ht = W1^T (h3 @ W2^T) per node -----------------------------------
__global__ __launch_bounds__(256) void k_ht(
    const float* __restrict__ h, const float* __restrict__ wf,
    int offW1, int offW2, float* __restrict__ Ht)
{
  const int t = threadIdx.x;
  const int n = blockIdx.x * 4 + (t >> 6);
  const int g = t & 63;
  const float w1_00 = wf[offW1 + 0], w1_01 = wf[offW1 + 1];
  const float w1_10 = wf[offW1 + 2], w1_11 = wf[offW1 + 3];
  float acc0 = 0.f, acc1 = 0.f;
  const float* wr = wf + offW2 + g * 64;
  const float* h0 = h + n * HID;
  for (int kk = 0; kk < 64; kk += 4) {
    float4 wv = *(const float4*)(wr + kk);
    float4 p0 = *(const float4*)(h0 + kk);
    float4 p1 = *(const float4*)(h0 + 64 + kk);
    acc0 += p0.x*wv.x + p0.y*wv.y + p0.z*wv.z + p0.w*wv.w;
    acc1 += p1.x*wv.x + p1.y*wv.y + p1.z*wv.z + p1.w*wv.w;
  }
  Ht[n * HID + g]      = w1_00 * acc0 + w1_10 * acc1;
  Ht[n * HID + 64 + g] = w1_01 * acc0 + w1_11 * acc1;
}

// ---- K6b: acc[src] += off_n[e] @ Ht[dst] -----------------------------------
__global__ __launch_bounds__(256) void k_msgs(
    const float* __restrict__ off_n, const int* __restrict__ ei,
    const float* __restrict__ Ht, float* __restrict__ acc)
{
  const int t = threadIdx.x;
  const int e = blockIdx.x * 4 + (t >> 6);
  const int g = t & 63;
  float4 o = *(const float4*)(off_n + e * 4);
  const int sn = ei[e], dn = ei[E_DIR + e];
  float ht0 = Ht[dn * HID + g], ht1 = Ht[dn * HID + 64 + g];
  atomicAdd(&acc[sn * HID + g],      o.x * ht0 + o.y * ht1);
  atomicAdd(&acc[sn * HID + 64 + g], o.z * ht0 + o.w * ht1);
}

// ---- K6c: h3 -= elu(diag_n @ Ht + acc) -------------------------------------
__global__ __launch_bounds__(256) void k_update(
    const float* __restrict__ diag_n, const float* __restrict__ Ht,
    const float* __restrict__ acc, float* h)
{
  const int i = blockIdx.x * 256 + threadIdx.x;   // over N*128
  const int n = i >> 7, r = i & 127, ii = r >> 6, g = r & 63;
  float4 dn = *(const float4*)(diag_n + n * 4);
  float ht0 = Ht[n * HID + g], ht1 = Ht[n * HID + 64 + g];
  float lh = (ii == 0) ? (dn.x * ht0 + dn.y * ht1) : (dn.z * ht0 + dn.w * ht1);
  lh += acc[i];
  float e = (lh > 0.f) ? lh : (expf(lh) - 1.f);
  h[i] = h[i] - e;
}

// ---- K7: out = MLP_out(h3) [N,128] -> relu 64 -> 40 ------------------------
__global__ __launch_bounds__(256) void k_mlp_out(
    const float* __restrict__ h, const float* __restrict__ wf,
    const int* __restrict__ flag, void* __restrict__ outv)
{
  __shared__ float s_hid[4][68];
  const int t = threadIdx.x;
  const int n0 = blockIdx.x * 4;
  {
    const int n = t >> 6, j = t & 63;
    float acc = wf[OFF_BOUT1 + j];
    const float* hr = h + (n0 + n) * HID;
    const float* wr = wf + OFF_WOUT1 + j * HID;
    for (int kk = 0; kk < HID; kk += 4) {
      float4 wv = *(const float4*)(wr + kk);
      float4 hv = *(const float4*)(hr + kk);
      acc += hv.x*wv.x + hv.y*wv.y + hv.z*wv.z + hv.w*wv.w;
    }
    s_hid[n][j] = fmaxf(acc, 0.f);
  }
  __syncthreads();
  if (t < 160) {
    const int n = t / 40, o = t % 40;
    float acc = wf[OFF_BOUT2 + o];
    const float* wr = wf + OFF_WOUT2 + o * 64;
    #pragma unroll
    for (int j = 0; j < 64; j += 4) {
      float4 wv = *(const float4*)(wr + j);
      acc += s_hid[n][j]*wv.x + s_hid[n][j+1]*wv.y
           + s_hid[n][j+2]*wv.z + s_hid[n][j+3]*wv.w;
    }
    const int idx = (n0 + n) * OUTC + o;
    if (*flag) ((u16*)outv)[idx] = f2bf(acc);
    else       ((float*)outv)[idx] = acc;
  }
}

extern "C" void kernel_launch(void* const* d_in, const int* in_sizes, int n_in,
                              void* d_out, int out_size, void* d_ws, size_t ws_size,
                              hipStream_t stream)
{
  const int* ei = (const int*)d_in[1];

  float* ws   = (float*)d_ws;
  float* wf   = ws;                               // [0, 76928)
  int*   flag = (int*)(ws + 76928);
  float* h      = ws + 76944;                     // 2,560,000
  float* Ht     = h + 2560000;                    // 2,560,000
  float* off_n  = Ht + 2560000;                   // 1,280,000
  float* diag   = off_n + 1280000;                // 80,000
  float* Dinv   = diag + 80000;                   // 80,000
  float* diag_n = Dinv + 80000;                   // 80,000
  float* X      = diag_n + 80000;                 // 2,560,000 (maps, then acc)
  float* maps   = X;
  float* acc    = X;
  // u_s/u_d alias Ht (dead until diffusion loop)
  float* u_s    = Ht;
  float* u_d    = Ht + 1280000;

  P16 P;
  for (int i = 0; i < 16; ++i) P.p[i] = d_in[2 + i];

  k_sniff<<<1, 256, 0, stream>>>((const u16*)d_in[0], flag);
  k_convert<<<(WTOTAL + 255) / 256, 256, 0, stream>>>(P, flag, wf);
  hipMemsetAsync(diag, 0, 80000 * sizeof(float), stream);
  k_mlp_in<<<N_NODES / 4, 256, 0, stream>>>(d_in[0], flag, wf, h);
  k_uproj<<<N_NODES / 4, 256, 0, stream>>>(h, wf, u_s, u_d);
  k_edge_maps2<<<E_DIR / 64, 256, 0, stream>>>(u_s, u_d, ei, wf, maps);
  k_ftf_diag<<<E_DIR / 256, 256, 0, stream>>>(maps, ei, diag);
  k_norm<<<(N_NODES + 255) / 256, 256, 0, stream>>>(diag, Dinv, diag_n);
  k_offn<<<E_DIR / 256, 256, 0, stream>>>(maps, ei, Dinv, off_n);

  const int offW1s[2] = {OFF_W1_0, OFF_W1_1};
  const int offW2s[2] = {OFF_W2_0, OFF_W2_1};
  for (int l = 0; l < 2; ++l) {
    k_ht<<<N_NODES / 4, 256, 0, stream>>>(h, wf, offW1s[l], offW2s[l], Ht);
    hipMemsetAsync(acc, 0, 2560000 * sizeof(float), stream);
    k_msgs<<<E_DIR / 4, 256, 0, stream>>>(off_n, ei, Ht, acc);
    k_update<<<N_NODES * HID / 256, 256, 0, stream>>>(diag_n, Ht, acc, h);
  }
  k_mlp_out<<<N_NODES / 4, 256, 0, stream>>>(h, wf, flag, d_out);
}

// Round 4
// 743.184 us; speedup vs baseline: 3.1279x; 1.8831x over previous
//
#include <hip/hip_runtime.h>
#include <math.h>

#define N_NODES 20000
#define E_HALF  160000
#define E_DIR   320000
#define IN_C    512
#define HID     128
#define OUTC    40

typedef unsigned short u16;
typedef unsigned int   u32;

// f32 weight arena offsets (elements)
#define OFF_WIN1  0
#define OFF_BIN1  32768
#define OFF_WIN2  32832
#define OFF_BIN2  41024
#define OFF_WMAP1 41152
#define OFF_BMAP1 57536
#define OFF_WMAP2 57600
#define OFF_BMAP2 57856
#define OFF_WOUT1 57860
#define OFF_BOUT1 66052
#define OFF_WOUT2 66116
#define OFF_BOUT2 68676
#define OFF_W1_0  68716
#define OFF_W2_0  68720
#define OFF_W1_1  72816
#define OFF_W2_1  72820
#define WTOTAL    76916
// transposed (k-major) copies
#define OFF_W1T     76916
#define OFF_WIN2T   109684
#define OFF_WMAP1AT 117876
#define OFF_WMAP1BT 126068
#define OFF_W2_0T   134260
#define OFF_W2_1T   138356
#define OFF_WOUT1T  142452
#define TTOTAL      73728

__device__ __forceinline__ float bfu2f(u16 u) {
  union { u32 i; float f; } v; v.i = ((u32)u) << 16; return v.f;
}
__device__ __forceinline__ void unpack8(const uint4 c, float* f) {
  union { u32 i; float x; } v;
  v.i = c.x << 16;          f[0] = v.x;
  v.i = c.x & 0xffff0000u;  f[1] = v.x;
  v.i = c.y << 16;          f[2] = v.x;
  v.i = c.y & 0xffff0000u;  f[3] = v.x;
  v.i = c.z << 16;          f[4] = v.x;
  v.i = c.z & 0xffff0000u;  f[5] = v.x;
  v.i = c.w << 16;          f[6] = v.x;
  v.i = c.w & 0xffff0000u;  f[7] = v.x;
}
__device__ __forceinline__ u16 f2bf(float f) {
  union { float f; u32 u; } v; v.f = f;
  u32 u = v.u;
  u += 0x7fffu + ((u >> 16) & 1u);   // RNE
  return (u16)(u >> 16);
}

// ---- K0: sniff input float dtype. flag=1 -> bf16, flag=0 -> f32 ------------
__global__ void k_sniff(const u16* __restrict__ xv, int* __restrict__ flag) {
  __shared__ int s_bad;
  if (threadIdx.x == 0) s_bad = 0;
  __syncthreads();
  int bad = 0;
  for (int i = threadIdx.x; i < 2048; i += 256) {
    u16 u = xv[i];
    u32 ex = (u >> 7) & 0xFFu;
    if (!(ex >= 100 && ex <= 140) && (u & 0x7FFFu) != 0) bad++;
  }
  atomicAdd(&s_bad, bad);
  __syncthreads();
  if (threadIdx.x == 0) *flag = (s_bad < 64) ? 1 : 0;
}

// ---- K0b: convert all weights into an f32 arena ----------------------------
struct P16 { const void* p[16]; };
__global__ __launch_bounds__(256) void k_convert(P16 s, const int* __restrict__ flag,
                                                 float* __restrict__ dst) {
  const int offs[17] = {OFF_WIN1, OFF_BIN1, OFF_WIN2, OFF_BIN2, OFF_WMAP1,
                        OFF_BMAP1, OFF_WMAP2, OFF_BMAP2, OFF_WOUT1, OFF_BOUT1,
                        OFF_WOUT2, OFF_BOUT2, OFF_W1_0, OFF_W2_0, OFF_W1_1,
                        OFF_W2_1, WTOTAL};
  const int i = blockIdx.x * 256 + threadIdx.x;
  if (i >= WTOTAL) return;
  int sg = 0;
  #pragma unroll
  for (int k = 1; k < 16; ++k) if (i >= offs[k]) sg = k;
  const int j = i - offs[sg];
  float v;
  if (*flag) v = bfu2f(((const u16*)s.p[sg])[j]);
  else       v = ((const float*)s.p[sg])[j];
  dst[i] = v;
}

// ---- K0c: build k-major transposed weight copies ---------------------------
__global__ __launch_bounds__(256) void k_transpose(float* __restrict__ wf) {
  // {dst_off, src_off, J, src_stride, size}
  const int tab[7][5] = {
    {OFF_W1T,     OFF_WIN1,        64, 512, 32768},
    {OFF_WIN2T,   OFF_WIN2,       128,  64,  8192},
    {OFF_WMAP1AT, OFF_WMAP1,       64, 256,  8192},
    {OFF_WMAP1BT, OFF_WMAP1 + 128, 64, 256,  8192},
    {OFF_W2_0T,   OFF_W2_0,        64,  64,  4096},
    {OFF_W2_1T,   OFF_W2_1,        64,  64,  4096},
    {OFF_WOUT1T,  OFF_WOUT1,       64, 128,  8192}};
  int i = blockIdx.x * 256 + threadIdx.x;
  if (i >= TTOTAL) return;
  int sg = 0, base = 0;
  #pragma unroll
  for (int s = 0; s < 7; ++s) {
    if (i >= base && i < base + tab[s][4]) { sg = s; break; }
    base += tab[s][4];
  }
  const int local = i - base;
  const int J = tab[sg][2];
  const int k = local / J, j = local - k * J;
  wf[tab[sg][0] + local] = wf[tab[sg][1] + j * tab[sg][3] + k];
}

// ---- K1: h = MLP_in(x)  [N,512] -> relu 64 -> [N,128], LDS-tiled GEMM ------
// 64 nodes per block; layer1 4x4 outer-product tiles; fused layer2.
__global__ __launch_bounds__(256) void k_mlp_in(
    const void* __restrict__ xv, const int* __restrict__ flag,
    const float* __restrict__ wf, float* __restrict__ h)
{
  __shared__ float sbuf[64 * 76 + 64 * 68];   // stage1: xs[64][76] + wst[64][68]
  __shared__ float s_hid[64][68];             // layer1 activations
  float (*xs)[76]  = (float(*)[76])sbuf;
  float (*wst)[68] = (float(*)[68])(sbuf + 64 * 76);

  const int t = threadIdx.x;
  const int n0 = blockIdx.x * 64;
  const int jq = t & 15, nq = t >> 4;
  const int bf = *flag;

  float4 acc[4];
  #pragma unroll
  for (int i = 0; i < 4; ++i) acc[i] = make_float4(0.f, 0.f, 0.f, 0.f);

  for (int kc = 0; kc < IN_C; kc += 64) {
    __syncthreads();
    // stage x chunk (transpose-free: node-major rows, k-contiguous)
    {
      const int r0 = t >> 3, c = (t & 7) * 8;
      #pragma unroll
      for (int pp = 0; pp < 2; ++pp) {
        const int r = r0 + pp * 32;
        int node = n0 + r; if (node > N_NODES - 1) node = N_NODES - 1;
        if (bf) {
          uint4 xc = *(const uint4*)((const u16*)xv + (size_t)node * IN_C + kc + c);
          float f[8]; unpack8(xc, f);
          *(float4*)&xs[r][c]     = make_float4(f[0], f[1], f[2], f[3]);
          *(float4*)&xs[r][c + 4] = make_float4(f[4], f[5], f[6], f[7]);
        } else {
          const float* xr = (const float*)xv + (size_t)node * IN_C + kc + c;
          *(float4*)&xs[r][c]     = *(const float4*)xr;
          *(float4*)&xs[r][c + 4] = *(const float4*)(xr + 4);
        }
      }
    }
    // stage w1t chunk (k-major, contiguous 4096 floats)
    {
      const float* src = wf + OFF_W1T + kc * 64;
      #pragma unroll
      for (int pp = 0; pp < 4; ++pp) {
        const int flat = (pp * 256 + t) * 4;
        const int k = flat >> 6, j = flat & 63;
        *(float4*)&wst[k][j] = *(const float4*)(src + flat);
      }
    }
    __syncthreads();
    // compute: 4 nodes x 4 j per thread
    #pragma unroll 4
    for (int ks = 0; ks < 64; ks += 4) {
      float4 xr[4], wr[4];
      #pragma unroll
      for (int i = 0; i < 4; ++i) xr[i] = *(float4*)&xs[nq * 4 + i][ks];
      #pragma unroll
      for (int i = 0; i < 4; ++i) wr[i] = *(float4*)&wst[ks + i][jq * 4];
      #pragma unroll
      for (int i = 0; i < 4; ++i) {
        acc[i].x += xr[i].x*wr[0].x + xr[i].y*wr[1].x + xr[i].z*wr[2].x + xr[i].w*wr[3].x;
        acc[i].y += xr[i].x*wr[0].y + xr[i].y*wr[1].y + xr[i].z*wr[2].y + xr[i].w*wr[3].y;
        acc[i].z += xr[i].x*wr[0].z + xr[i].y*wr[1].z + xr[i].z*wr[2].z + xr[i].w*wr[3].z;
        acc[i].w += xr[i].x*wr[0].w + xr[i].y*wr[1].w + xr[i].z*wr[2].w + xr[i].w*wr[3].w;
      }
    }
  }
  // bias + relu -> s_hid
  {
    float4 b1v = *(const float4*)(wf + OFF_BIN1 + jq * 4);
    #pragma unroll
    for (int i = 0; i < 4; ++i) {
      float4 v;
      v.x = fmaxf(acc[i].x + b1v.x, 0.f);
      v.y = fmaxf(acc[i].y + b1v.y, 0.f);
      v.z = fmaxf(acc[i].z + b1v.z, 0.f);
      v.w = fmaxf(acc[i].w + b1v.w, 0.f);
      *(float4*)&s_hid[nq * 4 + i][jq * 4] = v;
    }
  }
  __syncthreads();
  // stage layer2 weights (k-major [64][128], 8192 floats) into sbuf alias
  {
    #pragma unroll
    for (int pp = 0; pp < 8; ++pp) {
      const int flat = (pp * 256 + t) * 4;
      *(float4*)(sbuf + flat) = *(const float4*)(wf + OFF_WIN2T + flat);
    }
  }
  __syncthreads();
  // layer2: 8 nodes x 4 outputs per thread
  {
    const int o4 = t & 31, og = o4 * 4, ng = t >> 5;
    float4 a2[8];
    #pragma unroll
    for (int i = 0; i < 8; ++i) a2[i] = make_float4(0.f, 0.f, 0.f, 0.f);
    #pragma unroll 4
    for (int k = 0; k < 64; k += 4) {
      float4 wv[4];
      #pragma unroll
      for (int i = 0; i < 4; ++i) wv[i] = *(float4*)(sbuf + (k + i) * 128 + og);
      #pragma unroll
      for (int ni = 0; ni < 8; ++ni) {
        float4 sv = *(float4*)&s_hid[ng * 8 + ni][k];
        a2[ni].x += sv.x*wv[0].x + sv.y*wv[1].x + sv.z*wv[2].x + sv.w*wv[3].x;
        a2[ni].y += sv.x*wv[0].y + sv.y*wv[1].y + sv.z*wv[2].y + sv.w*wv[3].y;
        a2[ni].z += sv.x*wv[0].z + sv.y*wv[1].z + sv.z*wv[2].z + sv.w*wv[3].z;
        a2[ni].w += sv.x*wv[0].w + sv.y*wv[1].w + sv.z*wv[2].w + sv.w*wv[3].w;
      }
    }
    float4 b2v = *(const float4*)(wf + OFF_BIN2 + og);
    #pragma unroll
    for (int ni = 0; ni < 8; ++ni) {
      const int node = n0 + ng * 8 + ni;
      if (node < N_NODES) {
        float4 v;
        v.x = a2[ni].x + b2v.x; v.y = a2[ni].y + b2v.y;
        v.z = a2[ni].z + b2v.z; v.w = a2[ni].w + b2v.w;
        *(float4*)&h[(size_t)node * HID + og] = v;
      }
    }
  }
}

// ---- K1b: u_s = h @ W1a^T, u_d = h @ W1b^T  (coalesced k-major weights) ----
__global__ __launch_bounds__(256) void k_uproj(
    const float* __restrict__ h, const float* __restrict__ wf,
    float* __restrict__ u_s, float* __restrict__ u_d)
{
  const int t = threadIdx.x;
  const int n = blockIdx.x * 4 + (t >> 6);
  const int j = t & 63;
  float as = 0.f, ad = 0.f;
  const float* hr = h + (size_t)n * HID;
  const float* wa = wf + OFF_WMAP1AT + j;
  const float* wb = wf + OFF_WMAP1BT + j;
  #pragma unroll 8
  for (int kk = 0; kk < 128; kk += 4) {
    float4 hv = *(const float4*)(hr + kk);
    const float* wa0 = wa + kk * 64;
    const float* wb0 = wb + kk * 64;
    as += hv.x*wa0[0] + hv.y*wa0[64] + hv.z*wa0[128] + hv.w*wa0[192];
    ad += hv.x*wb0[0] + hv.y*wb0[64] + hv.z*wb0[128] + hv.w*wb0[192];
  }
  u_s[n * 64 + j] = as;
  u_d[n * 64 + j] = ad;
}

// ---- K2: edge maps from node projections -----------------------------------
__global__ __launch_bounds__(256) void k_edge_maps2(
    const float* __restrict__ u_s, const float* __restrict__ u_d,
    const int* __restrict__ ei, const float* __restrict__ wf,
    float* __restrict__ maps)
{
  __shared__ float s_act[64][68];
  const int t = threadIdx.x;
  const int w = t >> 6, l = t & 63;
  const int e0 = blockIdx.x * 64;
  const float bias = wf[OFF_BMAP1 + l];
  const int eb = e0 + w * 16;
  #pragma unroll 4
  for (int i = 0; i < 16; ++i) {
    const int e = eb + i;
    const int sn = ei[e], dn = ei[E_DIR + e];
    float v = u_s[sn * 64 + l] + u_d[dn * 64 + l] + bias;
    s_act[w * 16 + i][l] = fmaxf(v, 0.f);
  }
  __syncthreads();
  const int ee = t >> 2, ko = t & 3;
  float acc = wf[OFF_BMAP2 + ko];
  const float* wr = wf + OFF_WMAP2 + ko * 64;
  #pragma unroll
  for (int j = 0; j < 64; j += 4) {
    float4 wv = *(const float4*)(wr + j);
    float4 av = *(const float4*)(&s_act[ee][j]);
    acc += av.x*wv.x + av.y*wv.y + av.z*wv.z + av.w*wv.w;
  }
  maps[(e0 + ee) * 4 + ko] = acc;
}

// ---- K3: diag[n] += F_e^T F_e over out-edges -------------------------------
__global__ __launch_bounds__(256) void k_ftf_diag(
    const float* __restrict__ maps, const int* __restrict__ ei,
    float* __restrict__ diag)
{
  const int e = blockIdx.x * 256 + threadIdx.x;
  if (e >= E_DIR) return;
  float4 m = *(const float4*)(maps + e * 4);
  float f00 = m.x * m.x + m.z * m.z;
  float f01 = m.x * m.y + m.z * m.w;
  float f11 = m.y * m.y + m.w * m.w;
  const int sn = ei[e];
  atomicAdd(&diag[sn * 4 + 0], f00);
  atomicAdd(&diag[sn * 4 + 1], f01);
  atomicAdd(&diag[sn * 4 + 3], f11);
}

// ---- K4: Dinv = diag^{-1/2} (2x2 sym eig, clip 1e-6), diag_n ---------------
__global__ void k_norm(const float* __restrict__ diag, float* __restrict__ Dinv,
                       float* __restrict__ diag_n)
{
  const int n = blockIdx.x * 256 + threadIdx.x;
  if (n >= N_NODES) return;
  float a = diag[n * 4 + 0], b = diag[n * 4 + 1], c = diag[n * 4 + 3];
  float mean = 0.5f * (a + c), diff = 0.5f * (a - c);
  float rad = sqrtf(diff * diff + b * b);
  float l1 = mean - rad, l2 = mean + rad;
  float s1 = 1.0f / sqrtf(fmaxf(l1, 1e-6f));
  float s2 = 1.0f / sqrtf(fmaxf(l2, 1e-6f));
  float D00, D01, D11;
  if (rad < 1e-20f) {
    float s = 1.0f / sqrtf(fmaxf(mean, 1e-6f));
    D00 = s; D01 = 0.f; D11 = s;
  } else {
    float vx, vy;
    if (diff >= 0.f) { vx = rad + diff; vy = b; }
    else             { vx = b;          vy = rad - diff; }
    float inv = 1.0f / sqrtf(vx * vx + vy * vy);
    float ux = vx * inv, uy = vy * inv;
    D00 = s1 * uy * uy + s2 * ux * ux;
    D01 = (s2 - s1) * ux * uy;
    D11 = s1 * ux * ux + s2 * uy * uy;
  }
  Dinv[n * 4 + 0] = D00; Dinv[n * 4 + 1] = D01;
  Dinv[n * 4 + 2] = D01; Dinv[n * 4 + 3] = D11;
  float t00 = D00 * a + D01 * b, t01 = D00 * b + D01 * c;
  float t10 = D01 * a + D11 * b, t11 = D01 * b + D11 * c;
  diag_n[n * 4 + 0] = t00 * D00 + t01 * D01;
  diag_n[n * 4 + 1] = t00 * D01 + t01 * D11;
  diag_n[n * 4 + 2] = t10 * D00 + t11 * D01;
  diag_n[n * 4 + 3] = t10 * D01 + t11 * D11;
}

// ---- K5: off_n = Dinv[src] * (-(F_e^T F_rev)) * Dinv[dst] ------------------
__global__ void k_offn(const float* __restrict__ maps, const int* __restrict__ ei,
                       const float* __restrict__ Dinv, float* __restrict__ off_n)
{
  const int e = blockIdx.x * 256 + threadIdx.x;
  if (e >= E_DIR) return;
  const int r = (e < E_HALF) ? (e + E_HALF) : (e - E_HALF);
  float4 me = *(const float4*)(maps + e * 4);
  float4 mr = *(const float4*)(maps + r * 4);
  float o00 = -(me.x * mr.x + me.z * mr.z);
  float o01 = -(me.x * mr.y + me.z * mr.w);
  float o10 = -(me.y * mr.x + me.w * mr.z);
  float o11 = -(me.y * mr.y + me.w * mr.w);
  const int sn = ei[e], dn = ei[E_DIR + e];
  float4 Ds = *(const float4*)(Dinv + sn * 4);
  float4 Dd = *(const float4*)(Dinv + dn * 4);
  float t00 = Ds.x * o00 + Ds.y * o10;
  float t01 = Ds.x * o01 + Ds.y * o11;
  float t10 = Ds.z * o00 + Ds.w * o10;
  float t11 = Ds.z * o01 + Ds.w * o11;
  float4 q;
  q.x = t00 * Dd.x + t01 * Dd.z;
  q.y = t00 * Dd.y + t01 * Dd.w;
  q.z = t10 * Dd.x + t11 * Dd.z;
  q.w = t10 * Dd.y + t11 * Dd.w;
  *(float4*)(off_n + e * 4) = q;
}

// ---- K6a: Ht = W1^T (h3 @ W2^T) per node (coalesced k-major W2) ------------
__global__ __launch_bounds__(256) void k_ht(
    const float* __restrict__ h, const float* __restrict__ wf,
    int offW1, int offW2T, float* __restrict__ Ht)
{
  const int t = threadIdx.x;
  const int n = blockIdx.x * 4 + (t >> 6);
  const int g = t & 63;
  const float w1_00 = wf[offW1 + 0], w1_01 = wf[offW1 + 1];
  const float w1_10 = wf[offW1 + 2], w1_11 = wf[offW1 + 3];
  float acc0 = 0.f, acc1 = 0.f;
  const float* wt = wf + offW2T + g;
  const float* h0 = h + (size_t)n * HID;
  #pragma unroll 4
  for (int kk = 0; kk < 64; kk += 4) {
    float4 p0 = *(const float4*)(h0 + kk);
    float4 p1 = *(const float4*)(h0 + 64 + kk);
    const float* w0 = wt + kk * 64;
    float wv0 = w0[0], wv1 = w0[64], wv2 = w0[128], wv3 = w0[192];
    acc0 += p0.x*wv0 + p0.y*wv1 + p0.z*wv2 + p0.w*wv3;
    acc1 += p1.x*wv0 + p1.y*wv1 + p1.z*wv2 + p1.w*wv3;
  }
  Ht[n * HID + g]      = w1_00 * acc0 + w1_10 * acc1;
  Ht[n * HID + 64 + g] = w1_01 * acc0 + w1_11 * acc1;
}

// ---- K6b: acc[src] += off_n[e] @ Ht[dst] -----------------------------------
__global__ __launch_bounds__(256) void k_msgs(
    const float* __restrict__ off_n, const int* __restrict__ ei,
    const float* __restrict__ Ht, float* __restrict__ acc)
{
  const int t = threadIdx.x;
  const int e = blockIdx.x * 4 + (t >> 6);
  const int g = t & 63;
  float4 o = *(const float4*)(off_n + e * 4);
  const int sn = ei[e], dn = ei[E_DIR + e];
  float ht0 = Ht[dn * HID + g], ht1 = Ht[dn * HID + 64 + g];
  atomicAdd(&acc[sn * HID + g],      o.x * ht0 + o.y * ht1);
  atomicAdd(&acc[sn * HID + 64 + g], o.z * ht0 + o.w * ht1);
}

// ---- K6c: h3 -= elu(diag_n @ Ht + acc) -------------------------------------
__global__ __launch_bounds__(256) void k_update(
    const float* __restrict__ diag_n, const float* __restrict__ Ht,
    const float* __restrict__ acc, float* h)
{
  const int i = blockIdx.x * 256 + threadIdx.x;
  const int n = i >> 7, r = i & 127, ii = r >> 6, g = r & 63;
  float4 dn = *(const float4*)(diag_n + n * 4);
  float ht0 = Ht[n * HID + g], ht1 = Ht[n * HID + 64 + g];
  float lh = (ii == 0) ? (dn.x * ht0 + dn.y * ht1) : (dn.z * ht0 + dn.w * ht1);
  lh += acc[i];
  float e = (lh > 0.f) ? lh : (expf(lh) - 1.f);
  h[i] = h[i] - e;
}

// ---- K7: out = MLP_out(h3) [N,128] -> relu 64 -> 40 ------------------------
__global__ __launch_bounds__(256) void k_mlp_out(
    const float* __restrict__ h, const float* __restrict__ wf,
    const int* __restrict__ flag, void* __restrict__ outv)
{
  __shared__ float s_hid[4][68];
  const int t = threadIdx.x;
  const int n0 = blockIdx.x * 4;
  {
    const int n = t >> 6, j = t & 63;
    float acc = wf[OFF_BOUT1 + j];
    const float* hr = h + (size_t)(n0 + n) * HID;
    const float* wt = wf + OFF_WOUT1T + j;
    #pragma unroll 8
    for (int kk = 0; kk < HID; kk += 4) {
      float4 hv = *(const float4*)(hr + kk);
      const float* w0 = wt + kk * 64;
      acc += hv.x*w0[0] + hv.y*w0[64] + hv.z*w0[128] + hv.w*w0[192];
    }
    s_hid[n][j] = fmaxf(acc, 0.f);
  }
  __syncthreads();
  if (t < 160) {
    const int n = t / 40, o = t % 40;
    float acc = wf[OFF_BOUT2 + o];
    const float* wr = wf + OFF_WOUT2 + o * 64;
    #pragma unroll
    for (int j = 0; j < 64; j += 4) {
      float4 wv = *(const float4*)(wr + j);
      acc += s_hid[n][j]*wv.x + s_hid[n][j+1]*wv.y
           + s_hid[n][j+2]*wv.z + s_hid[n][j+3]*wv.w;
    }
    const int idx = (n0 + n) * OUTC + o;
    if (*flag) ((u16*)outv)[idx] = f2bf(acc);
    else       ((float*)outv)[idx] = acc;
  }
}

extern "C" void kernel_launch(void* const* d_in, const int* in_sizes, int n_in,
                              void* d_out, int out_size, void* d_ws, size_t ws_size,
                              hipStream_t stream)
{
  const int* ei = (const int*)d_in[1];

  float* ws   = (float*)d_ws;
  float* wf   = ws;                               // [0, 150644) incl. transposes
  int*   flag = (int*)(ws + 150656);
  float* h      = ws + 150672;                    // 2,560,000
  float* Ht     = h + 2560000;                    // 2,560,000
  float* off_n  = Ht + 2560000;                   // 1,280,000
  float* diag   = off_n + 1280000;                // 80,000
  float* Dinv   = diag + 80000;                   // 80,000
  float* diag_n = Dinv + 80000;                   // 80,000
  float* X      = diag_n + 80000;                 // 2,560,000 (maps, then acc)
  float* maps   = X;
  float* acc    = X;
  float* u_s    = Ht;                             // alias (dead until diffusion)
  float* u_d    = Ht + 1280000;

  P16 P;
  for (int i = 0; i < 16; ++i) P.p[i] = d_in[2 + i];

  k_sniff<<<1, 256, 0, stream>>>((const u16*)d_in[0], flag);
  k_convert<<<(WTOTAL + 255) / 256, 256, 0, stream>>>(P, flag, wf);
  k_transpose<<<(TTOTAL + 255) / 256, 256, 0, stream>>>(wf);
  hipMemsetAsync(diag, 0, 80000 * sizeof(float), stream);
  k_mlp_in<<<(N_NODES + 63) / 64, 256, 0, stream>>>(d_in[0], flag, wf, h);
  k_uproj<<<N_NODES / 4, 256, 0, stream>>>(h, wf, u_s, u_d);
  k_edge_maps2<<<E_DIR / 64, 256, 0, stream>>>(u_s, u_d, ei, wf, maps);
  k_ftf_diag<<<E_DIR / 256, 256, 0, stream>>>(maps, ei, diag);
  k_norm<<<(N_NODES + 255) / 256, 256, 0, stream>>>(diag, Dinv, diag_n);
  k_offn<<<E_DIR / 256, 256, 0, stream>>>(maps, ei, Dinv, off_n);

  const int offW1s[2]  = {OFF_W1_0,  OFF_W1_1};
  const int offW2Ts[2] = {OFF_W2_0T, OFF_W2_1T};
  for (int l = 0; l < 2; ++l) {
    k_ht<<<N_NODES / 4, 256, 0, stream>>>(h, wf, offW1s[l], offW2Ts[l], Ht);
    hipMemsetAsync(acc, 0, 2560000 * sizeof(float), stream);
    k_msgs<<<E_DIR / 4, 256, 0, stream>>>(off_n, ei, Ht, acc);
    k_update<<<N_NODES * HID / 256, 256, 0, stream>>>(diag_n, Ht, acc, h);
  }
  k_mlp_out<<<N_NODES / 4, 256, 0, stream>>>(h, wf, flag, d_out);
}

// Round 5
// 614.097 us; speedup vs baseline: 3.7854x; 1.2102x over previous
//
#include <hip/hip_runtime.h>
#include <math.h>

#define N_NODES 20000
#define E_HALF  160000
#define E_DIR   320000
#define IN_C    512
#define HID     128
#define OUTC    40

typedef unsigned short u16;
typedef unsigned int   u32;

// f32 weight arena offsets (elements)
#define OFF_WIN1  0
#define OFF_BIN1  32768
#define OFF_WIN2  32832
#define OFF_BIN2  41024
#define OFF_WMAP1 41152
#define OFF_BMAP1 57536
#define OFF_WMAP2 57600
#define OFF_BMAP2 57856
#define OFF_WOUT1 57860
#define OFF_BOUT1 66052
#define OFF_WOUT2 66116
#define OFF_BOUT2 68676
#define OFF_W1_0  68716
#define OFF_W2_0  68720
#define OFF_W1_1  72816
#define OFF_W2_1  72820
#define WTOTAL    76916
// transposed (k-major) copies
#define OFF_W1T     76916
#define OFF_WIN2T   109684
#define OFF_WMAP1AT 117876
#define OFF_WMAP1BT 126068
#define OFF_W2_0T   134260
#define OFF_W2_1T   138356
#define OFF_WOUT1T  142452
#define TTOTAL      73728

__device__ __forceinline__ float bfu2f(u16 u) {
  union { u32 i; float f; } v; v.i = ((u32)u) << 16; return v.f;
}
__device__ __forceinline__ void unpack8(const uint4 c, float* f) {
  union { u32 i; float x; } v;
  v.i = c.x << 16;          f[0] = v.x;
  v.i = c.x & 0xffff0000u;  f[1] = v.x;
  v.i = c.y << 16;          f[2] = v.x;
  v.i = c.y & 0xffff0000u;  f[3] = v.x;
  v.i = c.z << 16;          f[4] = v.x;
  v.i = c.z & 0xffff0000u;  f[5] = v.x;
  v.i = c.w << 16;          f[6] = v.x;
  v.i = c.w & 0xffff0000u;  f[7] = v.x;
}
__device__ __forceinline__ u16 f2bf(float f) {
  union { float f; u32 u; } v; v.f = f;
  u32 u = v.u;
  u += 0x7fffu + ((u >> 16) & 1u);   // RNE
  return (u16)(u >> 16);
}

// ---- K0: sniff input float dtype. flag=1 -> bf16, flag=0 -> f32 ------------
__global__ void k_sniff(const u16* __restrict__ xv, int* __restrict__ flag) {
  __shared__ int s_bad;
  if (threadIdx.x == 0) s_bad = 0;
  __syncthreads();
  int bad = 0;
  for (int i = threadIdx.x; i < 2048; i += 256) {
    u16 u = xv[i];
    u32 ex = (u >> 7) & 0xFFu;
    if (!(ex >= 100 && ex <= 140) && (u & 0x7FFFu) != 0) bad++;
  }
  atomicAdd(&s_bad, bad);
  __syncthreads();
  if (threadIdx.x == 0) *flag = (s_bad < 64) ? 1 : 0;
}

// ---- K0b: convert all weights into an f32 arena ----------------------------
struct P16 { const void* p[16]; };
__global__ __launch_bounds__(256) void k_convert(P16 s, const int* __restrict__ flag,
                                                 float* __restrict__ dst) {
  const int offs[17] = {OFF_WIN1, OFF_BIN1, OFF_WIN2, OFF_BIN2, OFF_WMAP1,
                        OFF_BMAP1, OFF_WMAP2, OFF_BMAP2, OFF_WOUT1, OFF_BOUT1,
                        OFF_WOUT2, OFF_BOUT2, OFF_W1_0, OFF_W2_0, OFF_W1_1,
                        OFF_W2_1, WTOTAL};
  const int i = blockIdx.x * 256 + threadIdx.x;
  if (i >= WTOTAL) return;
  int sg = 0;
  #pragma unroll
  for (int k = 1; k < 16; ++k) if (i >= offs[k]) sg = k;
  const int j = i - offs[sg];
  float v;
  if (*flag) v = bfu2f(((const u16*)s.p[sg])[j]);
  else       v = ((const float*)s.p[sg])[j];
  dst[i] = v;
}

// ---- K0c: build k-major transposed weight copies ---------------------------
__global__ __launch_bounds__(256) void k_transpose(float* __restrict__ wf) {
  const int tab[7][5] = {
    {OFF_W1T,     OFF_WIN1,        64, 512, 32768},
    {OFF_WIN2T,   OFF_WIN2,       128,  64,  8192},
    {OFF_WMAP1AT, OFF_WMAP1,       64, 256,  8192},
    {OFF_WMAP1BT, OFF_WMAP1 + 128, 64, 256,  8192},
    {OFF_W2_0T,   OFF_W2_0,        64,  64,  4096},
    {OFF_W2_1T,   OFF_W2_1,        64,  64,  4096},
    {OFF_WOUT1T,  OFF_WOUT1,       64, 128,  8192}};
  int i = blockIdx.x * 256 + threadIdx.x;
  if (i >= TTOTAL) return;
  int sg = 0, base = 0;
  #pragma unroll
  for (int s = 0; s < 7; ++s) {
    if (i >= base && i < base + tab[s][4]) { sg = s; break; }
    base += tab[s][4];
  }
  const int local = i - base;
  const int J = tab[sg][2];
  const int k = local / J, j = local - k * J;
  wf[tab[sg][0] + local] = wf[tab[sg][1] + j * tab[sg][3] + k];
}

// ---- K1: h = MLP_in(x)  [N,512] -> relu 64 -> [N,128], LDS-tiled GEMM ------
__global__ __launch_bounds__(256) void k_mlp_in(
    const void* __restrict__ xv, const int* __restrict__ flag,
    const float* __restrict__ wf, float* __restrict__ h)
{
  __shared__ float sbuf[64 * 76 + 64 * 68];
  __shared__ float s_hid[64][68];
  float (*xs)[76]  = (float(*)[76])sbuf;
  float (*wst)[68] = (float(*)[68])(sbuf + 64 * 76);

  const int t = threadIdx.x;
  const int n0 = blockIdx.x * 64;
  const int jq = t & 15, nq = t >> 4;
  const int bf = *flag;

  float4 acc[4];
  #pragma unroll
  for (int i = 0; i < 4; ++i) acc[i] = make_float4(0.f, 0.f, 0.f, 0.f);

  for (int kc = 0; kc < IN_C; kc += 64) {
    __syncthreads();
    {
      const int r0 = t >> 3, c = (t & 7) * 8;
      #pragma unroll
      for (int pp = 0; pp < 2; ++pp) {
        const int r = r0 + pp * 32;
        int node = n0 + r; if (node > N_NODES - 1) node = N_NODES - 1;
        if (bf) {
          uint4 xc = *(const uint4*)((const u16*)xv + (size_t)node * IN_C + kc + c);
          float f[8]; unpack8(xc, f);
          *(float4*)&xs[r][c]     = make_float4(f[0], f[1], f[2], f[3]);
          *(float4*)&xs[r][c + 4] = make_float4(f[4], f[5], f[6], f[7]);
        } else {
          const float* xr = (const float*)xv + (size_t)node * IN_C + kc + c;
          *(float4*)&xs[r][c]     = *(const float4*)xr;
          *(float4*)&xs[r][c + 4] = *(const float4*)(xr + 4);
        }
      }
    }
    {
      const float* src = wf + OFF_W1T + kc * 64;
      #pragma unroll
      for (int pp = 0; pp < 4; ++pp) {
        const int flat = (pp * 256 + t) * 4;
        const int k = flat >> 6, j = flat & 63;
        *(float4*)&wst[k][j] = *(const float4*)(src + flat);
      }
    }
    __syncthreads();
    #pragma unroll 4
    for (int ks = 0; ks < 64; ks += 4) {
      float4 xr[4], wr[4];
      #pragma unroll
      for (int i = 0; i < 4; ++i) xr[i] = *(float4*)&xs[nq * 4 + i][ks];
      #pragma unroll
      for (int i = 0; i < 4; ++i) wr[i] = *(float4*)&wst[ks + i][jq * 4];
      #pragma unroll
      for (int i = 0; i < 4; ++i) {
        acc[i].x += xr[i].x*wr[0].x + xr[i].y*wr[1].x + xr[i].z*wr[2].x + xr[i].w*wr[3].x;
        acc[i].y += xr[i].x*wr[0].y + xr[i].y*wr[1].y + xr[i].z*wr[2].y + xr[i].w*wr[3].y;
        acc[i].z += xr[i].x*wr[0].z + xr[i].y*wr[1].z + xr[i].z*wr[2].z + xr[i].w*wr[3].z;
        acc[i].w += xr[i].x*wr[0].w + xr[i].y*wr[1].w + xr[i].z*wr[2].w + xr[i].w*wr[3].w;
      }
    }
  }
  {
    float4 b1v = *(const float4*)(wf + OFF_BIN1 + jq * 4);
    #pragma unroll
    for (int i = 0; i < 4; ++i) {
      float4 v;
      v.x = fmaxf(acc[i].x + b1v.x, 0.f);
      v.y = fmaxf(acc[i].y + b1v.y, 0.f);
      v.z = fmaxf(acc[i].z + b1v.z, 0.f);
      v.w = fmaxf(acc[i].w + b1v.w, 0.f);
      *(float4*)&s_hid[nq * 4 + i][jq * 4] = v;
    }
  }
  __syncthreads();
  {
    #pragma unroll
    for (int pp = 0; pp < 8; ++pp) {
      const int flat = (pp * 256 + t) * 4;
      *(float4*)(sbuf + flat) = *(const float4*)(wf + OFF_WIN2T + flat);
    }
  }
  __syncthreads();
  {
    const int o4 = t & 31, og = o4 * 4, ng = t >> 5;
    float4 a2[8];
    #pragma unroll
    for (int i = 0; i < 8; ++i) a2[i] = make_float4(0.f, 0.f, 0.f, 0.f);
    #pragma unroll 4
    for (int k = 0; k < 64; k += 4) {
      float4 wv[4];
      #pragma unroll
      for (int i = 0; i < 4; ++i) wv[i] = *(float4*)(sbuf + (k + i) * 128 + og);
      #pragma unroll
      for (int ni = 0; ni < 8; ++ni) {
        float4 sv = *(float4*)&s_hid[ng * 8 + ni][k];
        a2[ni].x += sv.x*wv[0].x + sv.y*wv[1].x + sv.z*wv[2].x + sv.w*wv[3].x;
        a2[ni].y += sv.x*wv[0].y + sv.y*wv[1].y + sv.z*wv[2].y + sv.w*wv[3].y;
        a2[ni].z += sv.x*wv[0].z + sv.y*wv[1].z + sv.z*wv[2].z + sv.w*wv[3].z;
        a2[ni].w += sv.x*wv[0].w + sv.y*wv[1].w + sv.z*wv[2].w + sv.w*wv[3].w;
      }
    }
    float4 b2v = *(const float4*)(wf + OFF_BIN2 + og);
    #pragma unroll
    for (int ni = 0; ni < 8; ++ni) {
      const int node = n0 + ng * 8 + ni;
      if (node < N_NODES) {
        float4 v;
        v.x = a2[ni].x + b2v.x; v.y = a2[ni].y + b2v.y;
        v.z = a2[ni].z + b2v.z; v.w = a2[ni].w + b2v.w;
        *(float4*)&h[(size_t)node * HID + og] = v;
      }
    }
  }
}

// ---- K1b: u_s = h @ W1a^T, u_d = h @ W1b^T ---------------------------------
__global__ __launch_bounds__(256) void k_uproj(
    const float* __restrict__ h, const float* __restrict__ wf,
    float* __restrict__ u_s, float* __restrict__ u_d)
{
  const int t = threadIdx.x;
  const int n = blockIdx.x * 4 + (t >> 6);
  const int j = t & 63;
  float as = 0.f, ad = 0.f;
  const float* hr = h + (size_t)n * HID;
  const float* wa = wf + OFF_WMAP1AT + j;
  const float* wb = wf + OFF_WMAP1BT + j;
  #pragma unroll 8
  for (int kk = 0; kk < 128; kk += 4) {
    float4 hv = *(const float4*)(hr + kk);
    const float* wa0 = wa + kk * 64;
    const float* wb0 = wb + kk * 64;
    as += hv.x*wa0[0] + hv.y*wa0[64] + hv.z*wa0[128] + hv.w*wa0[192];
    ad += hv.x*wb0[0] + hv.y*wb0[64] + hv.z*wb0[128] + hv.w*wb0[192];
  }
  u_s[n * 64 + j] = as;
  u_d[n * 64 + j] = ad;
}

// ---- K2: edge maps from node projections -----------------------------------
__global__ __launch_bounds__(256) void k_edge_maps2(
    const float* __restrict__ u_s, const float* __restrict__ u_d,
    const int* __restrict__ ei, const float* __restrict__ wf,
    float* __restrict__ maps)
{
  __shared__ float s_act[64][68];
  const int t = threadIdx.x;
  const int w = t >> 6, l = t & 63;
  const int e0 = blockIdx.x * 64;
  const float bias = wf[OFF_BMAP1 + l];
  const int eb = e0 + w * 16;
  #pragma unroll 4
  for (int i = 0; i < 16; ++i) {
    const int e = eb + i;
    const int sn = ei[e], dn = ei[E_DIR + e];
    float v = u_s[sn * 64 + l] + u_d[dn * 64 + l] + bias;
    s_act[w * 16 + i][l] = fmaxf(v, 0.f);
  }
  __syncthreads();
  const int ee = t >> 2, ko = t & 3;
  float acc = wf[OFF_BMAP2 + ko];
  const float* wr = wf + OFF_WMAP2 + ko * 64;
  #pragma unroll
  for (int j = 0; j < 64; j += 4) {
    float4 wv = *(const float4*)(wr + j);
    float4 av = *(const float4*)(&s_act[ee][j]);
    acc += av.x*wv.x + av.y*wv.y + av.z*wv.z + av.w*wv.w;
  }
  maps[(e0 + ee) * 4 + ko] = acc;
}

// ---- K3: diag[n] += F_e^T F_e over out-edges; also deg histogram -----------
__global__ __launch_bounds__(256) void k_ftf_diag(
    const float* __restrict__ maps, const int* __restrict__ ei,
    float* __restrict__ diag, int* __restrict__ deg)
{
  const int e = blockIdx.x * 256 + threadIdx.x;
  if (e >= E_DIR) return;
  float4 m = *(const float4*)(maps + e * 4);
  float f00 = m.x * m.x + m.z * m.z;
  float f01 = m.x * m.y + m.z * m.w;
  float f11 = m.y * m.y + m.w * m.w;
  const int sn = ei[e];
  atomicAdd(&diag[sn * 4 + 0], f00);
  atomicAdd(&diag[sn * 4 + 1], f01);
  atomicAdd(&diag[sn * 4 + 3], f11);
  atomicAdd(&deg[sn], 1);
}

// ---- K4: Dinv = diag^{-1/2} (2x2 sym eig, clip 1e-6), diag_n ---------------
__global__ void k_norm(const float* __restrict__ diag, float* __restrict__ Dinv,
                       float* __restrict__ diag_n)
{
  const int n = blockIdx.x * 256 + threadIdx.x;
  if (n >= N_NODES) return;
  float a = diag[n * 4 + 0], b = diag[n * 4 + 1], c = diag[n * 4 + 3];
  float mean = 0.5f * (a + c), diff = 0.5f * (a - c);
  float rad = sqrtf(diff * diff + b * b);
  float l1 = mean - rad, l2 = mean + rad;
  float s1 = 1.0f / sqrtf(fmaxf(l1, 1e-6f));
  float s2 = 1.0f / sqrtf(fmaxf(l2, 1e-6f));
  float D00, D01, D11;
  if (rad < 1e-20f) {
    float s = 1.0f / sqrtf(fmaxf(mean, 1e-6f));
    D00 = s; D01 = 0.f; D11 = s;
  } else {
    float vx, vy;
    if (diff >= 0.f) { vx = rad + diff; vy = b; }
    else             { vx = b;          vy = rad - diff; }
    float inv = 1.0f / sqrtf(vx * vx + vy * vy);
    float ux = vx * inv, uy = vy * inv;
    D00 = s1 * uy * uy + s2 * ux * ux;
    D01 = (s2 - s1) * ux * uy;
    D11 = s1 * ux * ux + s2 * uy * uy;
  }
  Dinv[n * 4 + 0] = D00; Dinv[n * 4 + 1] = D01;
  Dinv[n * 4 + 2] = D01; Dinv[n * 4 + 3] = D11;
  float t00 = D00 * a + D01 * b, t01 = D00 * b + D01 * c;
  float t10 = D01 * a + D11 * b, t11 = D01 * b + D11 * c;
  diag_n[n * 4 + 0] = t00 * D00 + t01 * D01;
  diag_n[n * 4 + 1] = t00 * D01 + t01 * D11;
  diag_n[n * 4 + 2] = t10 * D00 + t11 * D01;
  diag_n[n * 4 + 3] = t10 * D01 + t11 * D11;
}

// ---- K4b: exclusive scan of deg -> offsets (+cursor copy), 1 block ---------
__global__ __launch_bounds__(256) void k_scan(
    const int* __restrict__ deg, int* __restrict__ offsets,
    int* __restrict__ cursor)
{
  __shared__ int s[256];
  const int t = threadIdx.x;
  const int c0 = t * 79;
  int sum = 0;
  for (int i = 0; i < 79; ++i) {
    int idx = c0 + i;
    if (idx < N_NODES) sum += deg[idx];
  }
  s[t] = sum;
  __syncthreads();
  int run = sum;
  for (int off = 1; off < 256; off <<= 1) {
    int tmp = (t >= off) ? s[t - off] : 0;
    __syncthreads();
    s[t] += tmp;
    __syncthreads();
  }
  int base = s[t] - run;   // exclusive prefix of this chunk
  for (int i = 0; i < 79; ++i) {
    int idx = c0 + i;
    if (idx < N_NODES) {
      offsets[idx] = base;
      cursor[idx] = base;
      base += deg[idx];
    }
  }
  if (t == 255) offsets[N_NODES] = E_DIR;
}

// ---- K5: off_n into CSR slots (bucketed by src) ----------------------------
__global__ void k_offn_csr(const float* __restrict__ maps, const int* __restrict__ ei,
                           const float* __restrict__ Dinv, int* __restrict__ cursor,
                           int* __restrict__ csr_dst, float4* __restrict__ csr_off)
{
  const int e = blockIdx.x * 256 + threadIdx.x;
  if (e >= E_DIR) return;
  const int r = (e < E_HALF) ? (e + E_HALF) : (e - E_HALF);
  float4 me = *(const float4*)(maps + e * 4);
  float4 mr = *(const float4*)(maps + r * 4);
  float o00 = -(me.x * mr.x + me.z * mr.z);
  float o01 = -(me.x * mr.y + me.z * mr.w);
  float o10 = -(me.y * mr.x + me.w * mr.z);
  float o11 = -(me.y * mr.y + me.w * mr.w);
  const int sn = ei[e], dn = ei[E_DIR + e];
  float4 Ds = *(const float4*)(Dinv + sn * 4);
  float4 Dd = *(const float4*)(Dinv + dn * 4);
  float t00 = Ds.x * o00 + Ds.y * o10;
  float t01 = Ds.x * o01 + Ds.y * o11;
  float t10 = Ds.z * o00 + Ds.w * o10;
  float t11 = Ds.z * o01 + Ds.w * o11;
  float4 q;
  q.x = t00 * Dd.x + t01 * Dd.z;
  q.y = t00 * Dd.y + t01 * Dd.w;
  q.z = t10 * Dd.x + t11 * Dd.z;
  q.w = t10 * Dd.y + t11 * Dd.w;
  const int pos = atomicAdd(&cursor[sn], 1);
  csr_dst[pos] = dn;
  csr_off[pos] = q;
}

// ---- K6a: Ht = W1^T (h3 @ W2^T) per node -----------------------------------
__global__ __launch_bounds__(256) void k_ht(
    const float* __restrict__ h, const float* __restrict__ wf,
    int offW1, int offW2T, float* __restrict__ Ht)
{
  const int t = threadIdx.x;
  const int n = blockIdx.x * 4 + (t >> 6);
  const int g = t & 63;
  const float w1_00 = wf[offW1 + 0], w1_01 = wf[offW1 + 1];
  const float w1_10 = wf[offW1 + 2], w1_11 = wf[offW1 + 3];
  float acc0 = 0.f, acc1 = 0.f;
  const float* wt = wf + offW2T + g;
  const float* h0 = h + (size_t)n * HID;
  #pragma unroll 4
  for (int kk = 0; kk < 64; kk += 4) {
    float4 p0 = *(const float4*)(h0 + kk);
    float4 p1 = *(const float4*)(h0 + 64 + kk);
    const float* w0 = wt + kk * 64;
    float wv0 = w0[0], wv1 = w0[64], wv2 = w0[128], wv3 = w0[192];
    acc0 += p0.x*wv0 + p0.y*wv1 + p0.z*wv2 + p0.w*wv3;
    acc1 += p1.x*wv0 + p1.y*wv1 + p1.z*wv2 + p1.w*wv3;
  }
  Ht[n * HID + g]      = w1_00 * acc0 + w1_10 * acc1;
  Ht[n * HID + 64 + g] = w1_01 * acc0 + w1_11 * acc1;
}

// ---- K6b: per-node gather msgs + diag term + ELU + h update (fused) --------
// wave per node; lane g = feature g. No atomics, no acc buffer.
__global__ __launch_bounds__(256) void k_msgs_fused(
    const int* __restrict__ offsets, const int* __restrict__ csr_dst,
    const float4* __restrict__ csr_off, const float* __restrict__ diag_n,
    const float* __restrict__ Ht, float* __restrict__ h)
{
  const int n = blockIdx.x * 4 + (threadIdx.x >> 6);
  const int g = threadIdx.x & 63;
  const int s = offsets[n], e = offsets[n + 1];
  float acc0 = 0.f, acc1 = 0.f;
  int d_next = (s < e) ? csr_dst[s] : 0;
  float4 o_next = (s < e) ? csr_off[s] : make_float4(0.f, 0.f, 0.f, 0.f);
  for (int k = s; k < e; ++k) {
    const int d = d_next;
    const float4 o = o_next;
    if (k + 1 < e) { d_next = csr_dst[k + 1]; o_next = csr_off[k + 1]; }
    const float ht0 = Ht[(size_t)d * HID + g];
    const float ht1 = Ht[(size_t)d * HID + 64 + g];
    acc0 += o.x * ht0 + o.y * ht1;
    acc1 += o.z * ht0 + o.w * ht1;
  }
  const float4 dn = *(const float4*)(diag_n + n * 4);
  const float ht0 = Ht[(size_t)n * HID + g];
  const float ht1 = Ht[(size_t)n * HID + 64 + g];
  float lh0 = dn.x * ht0 + dn.y * ht1 + acc0;
  float lh1 = dn.z * ht0 + dn.w * ht1 + acc1;
  lh0 = (lh0 > 0.f) ? lh0 : (expf(lh0) - 1.f);
  lh1 = (lh1 > 0.f) ? lh1 : (expf(lh1) - 1.f);
  h[(size_t)n * HID + g]      -= lh0;
  h[(size_t)n * HID + 64 + g] -= lh1;
}

// ---- K7: out = MLP_out(h3) [N,128] -> relu 64 -> 40 ------------------------
__global__ __launch_bounds__(256) void k_mlp_out(
    const float* __restrict__ h, const float* __restrict__ wf,
    const int* __restrict__ flag, void* __restrict__ outv)
{
  __shared__ float s_hid[4][68];
  const int t = threadIdx.x;
  const int n0 = blockIdx.x * 4;
  {
    const int n = t >> 6, j = t & 63;
    float acc = wf[OFF_BOUT1 + j];
    const float* hr = h + (size_t)(n0 + n) * HID;
    const float* wt = wf + OFF_WOUT1T + j;
    #pragma unroll 8
    for (int kk = 0; kk < HID; kk += 4) {
      float4 hv = *(const float4*)(hr + kk);
      const float* w0 = wt + kk * 64;
      acc += hv.x*w0[0] + hv.y*w0[64] + hv.z*w0[128] + hv.w*w0[192];
    }
    s_hid[n][j] = fmaxf(acc, 0.f);
  }
  __syncthreads();
  if (t < 160) {
    const int n = t / 40, o = t % 40;
    float acc = wf[OFF_BOUT2 + o];
    const float* wr = wf + OFF_WOUT2 + o * 64;
    #pragma unroll
    for (int j = 0; j < 64; j += 4) {
      float4 wv = *(const float4*)(wr + j);
      acc += s_hid[n][j]*wv.x + s_hid[n][j+1]*wv.y
           + s_hid[n][j+2]*wv.z + s_hid[n][j+3]*wv.w;
    }
    const int idx = (n0 + n) * OUTC + o;
    if (*flag) ((u16*)outv)[idx] = f2bf(acc);
    else       ((float*)outv)[idx] = acc;
  }
}

extern "C" void kernel_launch(void* const* d_in, const int* in_sizes, int n_in,
                              void* d_out, int out_size, void* d_ws, size_t ws_size,
                              hipStream_t stream)
{
  const int* ei = (const int*)d_in[1];

  float* ws   = (float*)d_ws;
  float* wf   = ws;                               // [0, 150644) incl. transposes
  int*   flag = (int*)(ws + 150656);
  float* h      = ws + 150672;                    // 2,560,000
  float* Ht     = h + 2560000;                    // 2,560,000
  float* csr_offv = Ht + 2560000;                 // 1,280,000 (float4[E_DIR])
  float* diag   = csr_offv + 1280000;             // 80,000
  float* Dinv   = diag + 80000;                   // 80,000
  float* diag_n = Dinv + 80000;                   // 80,000
  float* X      = diag_n + 80000;                 // maps + CSR index arrays
  float* maps   = X;                              // 1,280,000 floats
  int*   csr_dst = (int*)(X + 1280000);           // 320,000 ints
  int*   offsets = (int*)(X + 1600000);           // 20,001 ints
  int*   cursor  = (int*)(X + 1620002);           // 20,000 ints
  int*   deg     = (int*)(X + 1640002);           // 20,000 ints
  float* u_s    = Ht;                             // alias (dead until k_ht)
  float* u_d    = Ht + 1280000;
  float4* csr_off = (float4*)csr_offv;

  P16 P;
  for (int i = 0; i < 16; ++i) P.p[i] = d_in[2 + i];

  k_sniff<<<1, 256, 0, stream>>>((const u16*)d_in[0], flag);
  k_convert<<<(WTOTAL + 255) / 256, 256, 0, stream>>>(P, flag, wf);
  k_transpose<<<(TTOTAL + 255) / 256, 256, 0, stream>>>(wf);
  hipMemsetAsync(diag, 0, 80000 * sizeof(float), stream);
  hipMemsetAsync(deg, 0, 20000 * sizeof(int), stream);
  k_mlp_in<<<(N_NODES + 63) / 64, 256, 0, stream>>>(d_in[0], flag, wf, h);
  k_uproj<<<N_NODES / 4, 256, 0, stream>>>(h, wf, u_s, u_d);
  k_edge_maps2<<<E_DIR / 64, 256, 0, stream>>>(u_s, u_d, ei, wf, maps);
  k_ftf_diag<<<E_DIR / 256, 256, 0, stream>>>(maps, ei, diag, deg);
  k_norm<<<(N_NODES + 255) / 256, 256, 0, stream>>>(diag, Dinv, diag_n);
  k_scan<<<1, 256, 0, stream>>>(deg, offsets, cursor);
  k_offn_csr<<<E_DIR / 256, 256, 0, stream>>>(maps, ei, Dinv, cursor, csr_dst, csr_off);

  const int offW1s[2]  = {OFF_W1_0,  OFF_W1_1};
  const int offW2Ts[2] = {OFF_W2_0T, OFF_W2_1T};
  for (int l = 0; l < 2; ++l) {
    k_ht<<<N_NODES / 4, 256, 0, stream>>>(h, wf, offW1s[l], offW2Ts[l], Ht);
    k_msgs_fused<<<N_NODES / 4, 256, 0, stream>>>(offsets, csr_dst, csr_off,
                                                  diag_n, Ht, h);
  }
  k_mlp_out<<<N_NODES / 4, 256, 0, stream>>>(h, wf, flag, d_out);
}

// Round 6
// 573.167 us; speedup vs baseline: 4.0557x; 1.0714x over previous
//
#include <hip/hip_runtime.h>
#include <math.h>

#define N_NODES 20000
#define E_HALF  160000
#define E_DIR   320000
#define IN_C    512
#define HID     128
#define OUTC    40

typedef unsigned short u16;
typedef unsigned int   u32;

// f32 weight arena offsets (elements)
#define OFF_WIN1  0
#define OFF_BIN1  32768
#define OFF_WIN2  32832
#define OFF_BIN2  41024
#define OFF_WMAP1 41152
#define OFF_BMAP1 57536
#define OFF_WMAP2 57600
#define OFF_BMAP2 57856
#define OFF_WOUT1 57860
#define OFF_BOUT1 66052
#define OFF_WOUT2 66116
#define OFF_BOUT2 68676
#define OFF_W1_0  68716
#define OFF_W2_0  68720
#define OFF_W1_1  72816
#define OFF_W2_1  72820
#define WTOTAL    76916
// transposed (k-major) copies
#define OFF_W1T     76916
#define OFF_WIN2T   109684
#define OFF_WMAP1AT 117876
#define OFF_WMAP1BT 126068
#define OFF_W2_0T   134260
#define OFF_W2_1T   138356
#define OFF_WOUT1T  142452
#define TTOTAL      73728

__device__ __forceinline__ float bfu2f(u16 u) {
  union { u32 i; float f; } v; v.i = ((u32)u) << 16; return v.f;
}
__device__ __forceinline__ void unpack8(const uint4 c, float* f) {
  union { u32 i; float x; } v;
  v.i = c.x << 16;          f[0] = v.x;
  v.i = c.x & 0xffff0000u;  f[1] = v.x;
  v.i = c.y << 16;          f[2] = v.x;
  v.i = c.y & 0xffff0000u;  f[3] = v.x;
  v.i = c.z << 16;          f[4] = v.x;
  v.i = c.z & 0xffff0000u;  f[5] = v.x;
  v.i = c.w << 16;          f[6] = v.x;
  v.i = c.w & 0xffff0000u;  f[7] = v.x;
}
__device__ __forceinline__ u16 f2bf(float f) {
  union { float f; u32 u; } v; v.f = f;
  u32 u = v.u;
  u += 0x7fffu + ((u >> 16) & 1u);   // RNE
  return (u16)(u >> 16);
}

// ---- K0: sniff input float dtype. flag=1 -> bf16, flag=0 -> f32 ------------
__global__ void k_sniff(const u16* __restrict__ xv, int* __restrict__ flag) {
  __shared__ int s_bad;
  if (threadIdx.x == 0) s_bad = 0;
  __syncthreads();
  int bad = 0;
  for (int i = threadIdx.x; i < 2048; i += 256) {
    u16 u = xv[i];
    u32 ex = (u >> 7) & 0xFFu;
    if (!(ex >= 100 && ex <= 140) && (u & 0x7FFFu) != 0) bad++;
  }
  atomicAdd(&s_bad, bad);
  __syncthreads();
  if (threadIdx.x == 0) *flag = (s_bad < 64) ? 1 : 0;
}

// ---- K0b: convert all weights into an f32 arena ----------------------------
struct P16 { const void* p[16]; };
__global__ __launch_bounds__(256) void k_convert(P16 s, const int* __restrict__ flag,
                                                 float* __restrict__ dst) {
  const int offs[17] = {OFF_WIN1, OFF_BIN1, OFF_WIN2, OFF_BIN2, OFF_WMAP1,
                        OFF_BMAP1, OFF_WMAP2, OFF_BMAP2, OFF_WOUT1, OFF_BOUT1,
                        OFF_WOUT2, OFF_BOUT2, OFF_W1_0, OFF_W2_0, OFF_W1_1,
                        OFF_W2_1, WTOTAL};
  const int i = blockIdx.x * 256 + threadIdx.x;
  if (i >= WTOTAL) return;
  int sg = 0;
  #pragma unroll
  for (int k = 1; k < 16; ++k) if (i >= offs[k]) sg = k;
  const int j = i - offs[sg];
  float v;
  if (*flag) v = bfu2f(((const u16*)s.p[sg])[j]);
  else       v = ((const float*)s.p[sg])[j];
  dst[i] = v;
}

// ---- K0c: build k-major transposed weight copies ---------------------------
__global__ __launch_bounds__(256) void k_transpose(float* __restrict__ wf) {
  const int tab[7][5] = {
    {OFF_W1T,     OFF_WIN1,        64, 512, 32768},
    {OFF_WIN2T,   OFF_WIN2,       128,  64,  8192},
    {OFF_WMAP1AT, OFF_WMAP1,       64, 256,  8192},
    {OFF_WMAP1BT, OFF_WMAP1 + 128, 64, 256,  8192},
    {OFF_W2_0T,   OFF_W2_0,        64,  64,  4096},
    {OFF_W2_1T,   OFF_W2_1,        64,  64,  4096},
    {OFF_WOUT1T,  OFF_WOUT1,       64, 128,  8192}};
  int i = blockIdx.x * 256 + threadIdx.x;
  if (i >= TTOTAL) return;
  int sg = 0, base = 0;
  #pragma unroll
  for (int s = 0; s < 7; ++s) {
    if (i >= base && i < base + tab[s][4]) { sg = s; break; }
    base += tab[s][4];
  }
  const int local = i - base;
  const int J = tab[sg][2];
  const int k = local / J, j = local - k * J;
  wf[tab[sg][0] + local] = wf[tab[sg][1] + j * tab[sg][3] + k];
}

// ---- K1: h = MLP_in(x)  [N,512] -> relu 64 -> [N,128], LDS-tiled GEMM ------
__global__ __launch_bounds__(256) void k_mlp_in(
    const void* __restrict__ xv, const int* __restrict__ flag,
    const float* __restrict__ wf, float* __restrict__ h)
{
  __shared__ float sbuf[64 * 76 + 64 * 68];
  __shared__ float s_hid[64][68];
  float (*xs)[76]  = (float(*)[76])sbuf;
  float (*wst)[68] = (float(*)[68])(sbuf + 64 * 76);

  const int t = threadIdx.x;
  const int n0 = blockIdx.x * 64;
  const int jq = t & 15, nq = t >> 4;
  const int bf = *flag;

  float4 acc[4];
  #pragma unroll
  for (int i = 0; i < 4; ++i) acc[i] = make_float4(0.f, 0.f, 0.f, 0.f);

  for (int kc = 0; kc < IN_C; kc += 64) {
    __syncthreads();
    {
      const int r0 = t >> 3, c = (t & 7) * 8;
      #pragma unroll
      for (int pp = 0; pp < 2; ++pp) {
        const int r = r0 + pp * 32;
        int node = n0 + r; if (node > N_NODES - 1) node = N_NODES - 1;
        if (bf) {
          uint4 xc = *(const uint4*)((const u16*)xv + (size_t)node * IN_C + kc + c);
          float f[8]; unpack8(xc, f);
          *(float4*)&xs[r][c]     = make_float4(f[0], f[1], f[2], f[3]);
          *(float4*)&xs[r][c + 4] = make_float4(f[4], f[5], f[6], f[7]);
        } else {
          const float* xr = (const float*)xv + (size_t)node * IN_C + kc + c;
          *(float4*)&xs[r][c]     = *(const float4*)xr;
          *(float4*)&xs[r][c + 4] = *(const float4*)(xr + 4);
        }
      }
    }
    {
      const float* src = wf + OFF_W1T + kc * 64;
      #pragma unroll
      for (int pp = 0; pp < 4; ++pp) {
        const int flat = (pp * 256 + t) * 4;
        const int k = flat >> 6, j = flat & 63;
        *(float4*)&wst[k][j] = *(const float4*)(src + flat);
      }
    }
    __syncthreads();
    #pragma unroll 4
    for (int ks = 0; ks < 64; ks += 4) {
      float4 xr[4], wr[4];
      #pragma unroll
      for (int i = 0; i < 4; ++i) xr[i] = *(float4*)&xs[nq * 4 + i][ks];
      #pragma unroll
      for (int i = 0; i < 4; ++i) wr[i] = *(float4*)&wst[ks + i][jq * 4];
      #pragma unroll
      for (int i = 0; i < 4; ++i) {
        acc[i].x += xr[i].x*wr[0].x + xr[i].y*wr[1].x + xr[i].z*wr[2].x + xr[i].w*wr[3].x;
        acc[i].y += xr[i].x*wr[0].y + xr[i].y*wr[1].y + xr[i].z*wr[2].y + xr[i].w*wr[3].y;
        acc[i].z += xr[i].x*wr[0].z + xr[i].y*wr[1].z + xr[i].z*wr[2].z + xr[i].w*wr[3].z;
        acc[i].w += xr[i].x*wr[0].w + xr[i].y*wr[1].w + xr[i].z*wr[2].w + xr[i].w*wr[3].w;
      }
    }
  }
  {
    float4 b1v = *(const float4*)(wf + OFF_BIN1 + jq * 4);
    #pragma unroll
    for (int i = 0; i < 4; ++i) {
      float4 v;
      v.x = fmaxf(acc[i].x + b1v.x, 0.f);
      v.y = fmaxf(acc[i].y + b1v.y, 0.f);
      v.z = fmaxf(acc[i].z + b1v.z, 0.f);
      v.w = fmaxf(acc[i].w + b1v.w, 0.f);
      *(float4*)&s_hid[nq * 4 + i][jq * 4] = v;
    }
  }
  __syncthreads();
  {
    #pragma unroll
    for (int pp = 0; pp < 8; ++pp) {
      const int flat = (pp * 256 + t) * 4;
      *(float4*)(sbuf + flat) = *(const float4*)(wf + OFF_WIN2T + flat);
    }
  }
  __syncthreads();
  {
    const int o4 = t & 31, og = o4 * 4, ng = t >> 5;
    float4 a2[8];
    #pragma unroll
    for (int i = 0; i < 8; ++i) a2[i] = make_float4(0.f, 0.f, 0.f, 0.f);
    #pragma unroll 4
    for (int k = 0; k < 64; k += 4) {
      float4 wv[4];
      #pragma unroll
      for (int i = 0; i < 4; ++i) wv[i] = *(float4*)(sbuf + (k + i) * 128 + og);
      #pragma unroll
      for (int ni = 0; ni < 8; ++ni) {
        float4 sv = *(float4*)&s_hid[ng * 8 + ni][k];
        a2[ni].x += sv.x*wv[0].x + sv.y*wv[1].x + sv.z*wv[2].x + sv.w*wv[3].x;
        a2[ni].y += sv.x*wv[0].y + sv.y*wv[1].y + sv.z*wv[2].y + sv.w*wv[3].y;
        a2[ni].z += sv.x*wv[0].z + sv.y*wv[1].z + sv.z*wv[2].z + sv.w*wv[3].z;
        a2[ni].w += sv.x*wv[0].w + sv.y*wv[1].w + sv.z*wv[2].w + sv.w*wv[3].w;
      }
    }
    float4 b2v = *(const float4*)(wf + OFF_BIN2 + og);
    #pragma unroll
    for (int ni = 0; ni < 8; ++ni) {
      const int node = n0 + ng * 8 + ni;
      if (node < N_NODES) {
        float4 v;
        v.x = a2[ni].x + b2v.x; v.y = a2[ni].y + b2v.y;
        v.z = a2[ni].z + b2v.z; v.w = a2[ni].w + b2v.w;
        *(float4*)&h[(size_t)node * HID + og] = v;
      }
    }
  }
}

// ---- K1b: u_s = h @ W1a^T, u_d = h @ W1b^T ---------------------------------
__global__ __launch_bounds__(256) void k_uproj(
    const float* __restrict__ h, const float* __restrict__ wf,
    float* __restrict__ u_s, float* __restrict__ u_d)
{
  const int t = threadIdx.x;
  const int n = blockIdx.x * 4 + (t >> 6);
  const int j = t & 63;
  float as = 0.f, ad = 0.f;
  const float* hr = h + (size_t)n * HID;
  const float* wa = wf + OFF_WMAP1AT + j;
  const float* wb = wf + OFF_WMAP1BT + j;
  #pragma unroll 8
  for (int kk = 0; kk < 128; kk += 4) {
    float4 hv = *(const float4*)(hr + kk);
    const float* wa0 = wa + kk * 64;
    const float* wb0 = wb + kk * 64;
    as += hv.x*wa0[0] + hv.y*wa0[64] + hv.z*wa0[128] + hv.w*wa0[192];
    ad += hv.x*wb0[0] + hv.y*wb0[64] + hv.z*wb0[128] + hv.w*wb0[192];
  }
  u_s[n * 64 + j] = as;
  u_d[n * 64 + j] = ad;
}

// ---- K2: edge maps from node projections; deg histogram fused --------------
__global__ __launch_bounds__(256) void k_edge_maps2(
    const float* __restrict__ u_s, const float* __restrict__ u_d,
    const int* __restrict__ ei, const float* __restrict__ wf,
    float* __restrict__ maps, int* __restrict__ deg)
{
  __shared__ float s_act[64][68];
  const int t = threadIdx.x;
  const int w = t >> 6, l = t & 63;
  const int e0 = blockIdx.x * 64;
  const float bias = wf[OFF_BMAP1 + l];
  const int eb = e0 + w * 16;
  if (l < 16) atomicAdd(&deg[ei[eb + l]], 1);
  #pragma unroll 4
  for (int i = 0; i < 16; ++i) {
    const int e = eb + i;
    const int sn = ei[e], dn = ei[E_DIR + e];
    float v = u_s[sn * 64 + l] + u_d[dn * 64 + l] + bias;
    s_act[w * 16 + i][l] = fmaxf(v, 0.f);
  }
  __syncthreads();
  const int ee = t >> 2, ko = t & 3;
  float acc = wf[OFF_BMAP2 + ko];
  const float* wr = wf + OFF_WMAP2 + ko * 64;
  #pragma unroll
  for (int j = 0; j < 64; j += 4) {
    float4 wv = *(const float4*)(wr + j);
    float4 av = *(const float4*)(&s_act[ee][j]);
    acc += av.x*wv.x + av.y*wv.y + av.z*wv.z + av.w*wv.w;
  }
  maps[(e0 + ee) * 4 + ko] = acc;
}

// ---- K4b: exclusive scan of deg -> offsets (+cursor copy), 1 block ---------
__global__ __launch_bounds__(256) void k_scan(
    const int* __restrict__ deg, int* __restrict__ offsets,
    int* __restrict__ cursor)
{
  __shared__ int s[256];
  const int t = threadIdx.x;
  const int c0 = t * 79;
  int sum = 0;
  for (int i = 0; i < 79; ++i) {
    int idx = c0 + i;
    if (idx < N_NODES) sum += deg[idx];
  }
  s[t] = sum;
  __syncthreads();
  int run = sum;
  for (int off = 1; off < 256; off <<= 1) {
    int tmp = (t >= off) ? s[t - off] : 0;
    __syncthreads();
    s[t] += tmp;
    __syncthreads();
  }
  int base = s[t] - run;   // exclusive prefix of this chunk
  for (int i = 0; i < 79; ++i) {
    int idx = c0 + i;
    if (idx < N_NODES) {
      offsets[idx] = base;
      cursor[idx] = base;
      base += deg[idx];
    }
  }
  if (t == 255) offsets[N_NODES] = E_DIR;
}

// ---- K4c: bucket edges by src; record slot of each edge --------------------
__global__ __launch_bounds__(256) void k_csr_build(
    const int* __restrict__ ei, int* __restrict__ cursor,
    int* __restrict__ csr_eid, int* __restrict__ eslot)
{
  const int e = blockIdx.x * 256 + threadIdx.x;
  if (e >= E_DIR) return;
  const int sn = ei[e];
  const int pos = atomicAdd(&cursor[sn], 1);
  csr_eid[pos] = e;
  eslot[e] = pos;
}

// ---- K4d: per-node FtF gather + 2x2 eig -> Dinv, diag_n (no atomics) -------
__global__ __launch_bounds__(256) void k_ftf_norm(
    const float* __restrict__ maps, const int* __restrict__ offsets,
    const int* __restrict__ csr_eid, float* __restrict__ Dinv,
    float* __restrict__ diag_n)
{
  const int n = blockIdx.x * 256 + threadIdx.x;
  if (n >= N_NODES) return;
  const int s = offsets[n], e = offsets[n + 1];
  float a = 0.f, b = 0.f, c = 0.f;
  for (int p = s; p < e; ++p) {
    const int eid = csr_eid[p];
    float4 m = *(const float4*)(maps + (size_t)eid * 4);
    a += m.x * m.x + m.z * m.z;
    b += m.x * m.y + m.z * m.w;
    c += m.y * m.y + m.w * m.w;
  }
  float mean = 0.5f * (a + c), diff = 0.5f * (a - c);
  float rad = sqrtf(diff * diff + b * b);
  float l1 = mean - rad, l2 = mean + rad;
  float s1 = 1.0f / sqrtf(fmaxf(l1, 1e-6f));
  float s2 = 1.0f / sqrtf(fmaxf(l2, 1e-6f));
  float D00, D01, D11;
  if (rad < 1e-20f) {
    float s0 = 1.0f / sqrtf(fmaxf(mean, 1e-6f));
    D00 = s0; D01 = 0.f; D11 = s0;
  } else {
    float vx, vy;
    if (diff >= 0.f) { vx = rad + diff; vy = b; }
    else             { vx = b;          vy = rad - diff; }
    float inv = 1.0f / sqrtf(vx * vx + vy * vy);
    float ux = vx * inv, uy = vy * inv;
    D00 = s1 * uy * uy + s2 * ux * ux;
    D01 = (s2 - s1) * ux * uy;
    D11 = s1 * ux * ux + s2 * uy * uy;
  }
  Dinv[n * 4 + 0] = D00; Dinv[n * 4 + 1] = D01;
  Dinv[n * 4 + 2] = D01; Dinv[n * 4 + 3] = D11;
  float t00 = D00 * a + D01 * b, t01 = D00 * b + D01 * c;
  float t10 = D01 * a + D11 * b, t11 = D01 * b + D11 * c;
  diag_n[n * 4 + 0] = t00 * D00 + t01 * D01;
  diag_n[n * 4 + 1] = t00 * D01 + t01 * D11;
  diag_n[n * 4 + 2] = t10 * D00 + t11 * D01;
  diag_n[n * 4 + 3] = t10 * D01 + t11 * D11;
}

// ---- K5: off_n into CSR slots via eslot (no atomics) -----------------------
__global__ void k_offn2(const float* __restrict__ maps, const int* __restrict__ ei,
                        const float* __restrict__ Dinv, const int* __restrict__ eslot,
                        int* __restrict__ csr_dst, float4* __restrict__ csr_off)
{
  const int e = blockIdx.x * 256 + threadIdx.x;
  if (e >= E_DIR) return;
  const int r = (e < E_HALF) ? (e + E_HALF) : (e - E_HALF);
  float4 me = *(const float4*)(maps + (size_t)e * 4);
  float4 mr = *(const float4*)(maps + (size_t)r * 4);
  float o00 = -(me.x * mr.x + me.z * mr.z);
  float o01 = -(me.x * mr.y + me.z * mr.w);
  float o10 = -(me.y * mr.x + me.w * mr.z);
  float o11 = -(me.y * mr.y + me.w * mr.w);
  const int sn = ei[e], dn = ei[E_DIR + e];
  float4 Ds = *(const float4*)(Dinv + sn * 4);
  float4 Dd = *(const float4*)(Dinv + dn * 4);
  float t00 = Ds.x * o00 + Ds.y * o10;
  float t01 = Ds.x * o01 + Ds.y * o11;
  float t10 = Ds.z * o00 + Ds.w * o10;
  float t11 = Ds.z * o01 + Ds.w * o11;
  float4 q;
  q.x = t00 * Dd.x + t01 * Dd.z;
  q.y = t00 * Dd.y + t01 * Dd.w;
  q.z = t10 * Dd.x + t11 * Dd.z;
  q.w = t10 * Dd.y + t11 * Dd.w;
  const int pos = eslot[e];
  csr_dst[pos] = dn;
  csr_off[pos] = q;
}

// ---- K6a: Ht = W1^T (h3 @ W2^T) per node -----------------------------------
__global__ __launch_bounds__(256) void k_ht(
    const float* __restrict__ h, const float* __restrict__ wf,
    int offW1, int offW2T, float* __restrict__ Ht)
{
  const int t = threadIdx.x;
  const int n = blockIdx.x * 4 + (t >> 6);
  const int g = t & 63;
  const float w1_00 = wf[offW1 + 0], w1_01 = wf[offW1 + 1];
  const float w1_10 = wf[offW1 + 2], w1_11 = wf[offW1 + 3];
  float acc0 = 0.f, acc1 = 0.f;
  const float* wt = wf + offW2T + g;
  const float* h0 = h + (size_t)n * HID;
  #pragma unroll 4
  for (int kk = 0; kk < 64; kk += 4) {
    float4 p0 = *(const float4*)(h0 + kk);
    float4 p1 = *(const float4*)(h0 + 64 + kk);
    const float* w0 = wt + kk * 64;
    float wv0 = w0[0], wv1 = w0[64], wv2 = w0[128], wv3 = w0[192];
    acc0 += p0.x*wv0 + p0.y*wv1 + p0.z*wv2 + p0.w*wv3;
    acc1 += p1.x*wv0 + p1.y*wv1 + p1.z*wv2 + p1.w*wv3;
  }
  Ht[n * HID + g]      = w1_00 * acc0 + w1_10 * acc1;
  Ht[n * HID + 64 + g] = w1_01 * acc0 + w1_11 * acc1;
}

// ---- K6b: per-node gather msgs + diag term + ELU + h update (fused) --------
__global__ __launch_bounds__(256) void k_msgs_fused(
    const int* __restrict__ offsets, const int* __restrict__ csr_dst,
    const float4* __restrict__ csr_off, const float* __restrict__ diag_n,
    const float* __restrict__ Ht, float* __restrict__ h)
{
  const int n = blockIdx.x * 4 + (threadIdx.x >> 6);
  const int g = threadIdx.x & 63;
  const int s = offsets[n], e = offsets[n + 1];
  float acc0 = 0.f, acc1 = 0.f;
  int d_next = (s < e) ? csr_dst[s] : 0;
  float4 o_next = (s < e) ? csr_off[s] : make_float4(0.f, 0.f, 0.f, 0.f);
  for (int k = s; k < e; ++k) {
    const int d = d_next;
    const float4 o = o_next;
    if (k + 1 < e) { d_next = csr_dst[k + 1]; o_next = csr_off[k + 1]; }
    const float ht0 = Ht[(size_t)d * HID + g];
    const float ht1 = Ht[(size_t)d * HID + 64 + g];
    acc0 += o.x * ht0 + o.y * ht1;
    acc1 += o.z * ht0 + o.w * ht1;
  }
  const float4 dn = *(const float4*)(diag_n + n * 4);
  const float ht0 = Ht[(size_t)n * HID + g];
  const float ht1 = Ht[(size_t)n * HID + 64 + g];
  float lh0 = dn.x * ht0 + dn.y * ht1 + acc0;
  float lh1 = dn.z * ht0 + dn.w * ht1 + acc1;
  lh0 = (lh0 > 0.f) ? lh0 : (expf(lh0) - 1.f);
  lh1 = (lh1 > 0.f) ? lh1 : (expf(lh1) - 1.f);
  h[(size_t)n * HID + g]      -= lh0;
  h[(size_t)n * HID + 64 + g] -= lh1;
}

// ---- K7: out = MLP_out(h3) [N,128] -> relu 64 -> 40 ------------------------
__global__ __launch_bounds__(256) void k_mlp_out(
    const float* __restrict__ h, const float* __restrict__ wf,
    const int* __restrict__ flag, void* __restrict__ outv)
{
  __shared__ float s_hid[4][68];
  const int t = threadIdx.x;
  const int n0 = blockIdx.x * 4;
  {
    const int n = t >> 6, j = t & 63;
    float acc = wf[OFF_BOUT1 + j];
    const float* hr = h + (size_t)(n0 + n) * HID;
    const float* wt = wf + OFF_WOUT1T + j;
    #pragma unroll 8
    for (int kk = 0; kk < HID; kk += 4) {
      float4 hv = *(const float4*)(hr + kk);
      const float* w0 = wt + kk * 64;
      acc += hv.x*w0[0] + hv.y*w0[64] + hv.z*w0[128] + hv.w*w0[192];
    }
    s_hid[n][j] = fmaxf(acc, 0.f);
  }
  __syncthreads();
  if (t < 160) {
    const int n = t / 40, o = t % 40;
    float acc = wf[OFF_BOUT2 + o];
    const float* wr = wf + OFF_WOUT2 + o * 64;
    #pragma unroll
    for (int j = 0; j < 64; j += 4) {
      float4 wv = *(const float4*)(wr + j);
      acc += s_hid[n][j]*wv.x + s_hid[n][j+1]*wv.y
           + s_hid[n][j+2]*wv.z + s_hid[n][j+3]*wv.w;
    }
    const int idx = (n0 + n) * OUTC + o;
    if (*flag) ((u16*)outv)[idx] = f2bf(acc);
    else       ((float*)outv)[idx] = acc;
  }
}

extern "C" void kernel_launch(void* const* d_in, const int* in_sizes, int n_in,
                              void* d_out, int out_size, void* d_ws, size_t ws_size,
                              hipStream_t stream)
{
  const int* ei = (const int*)d_in[1];

  float* ws   = (float*)d_ws;
  float* wf   = ws;                               // [0, 150644) incl. transposes
  int*   flag = (int*)(ws + 150656);
  float* h      = ws + 150672;                    // 2,560,000
  float* Ht     = h + 2560000;                    // 2,560,000
  float* csr_offv = Ht + 2560000;                 // 1,280,000 (float4[E_DIR])
  float* Dinv   = csr_offv + 1280000;             // 80,000
  float* diag_n = Dinv + 80000;                   // 80,000
  float* X      = diag_n + 80000;                 // maps + CSR index arrays
  float* maps   = X;                              // 1,280,000 floats
  int*   csr_dst = (int*)(X + 1280000);           // 320,000
  int*   csr_eid = (int*)(X + 1600000);           // 320,000
  int*   eslot   = (int*)(X + 1920000);           // 320,000
  int*   offsets = (int*)(X + 2240000);           // 20,001
  int*   cursor  = (int*)(X + 2260002);           // 20,000
  int*   deg     = (int*)(X + 2280002);           // 20,000
  float* u_s    = Ht;                             // alias (dead until k_ht)
  float* u_d    = Ht + 1280000;
  float4* csr_off = (float4*)csr_offv;

  P16 P;
  for (int i = 0; i < 16; ++i) P.p[i] = d_in[2 + i];

  k_sniff<<<1, 256, 0, stream>>>((const u16*)d_in[0], flag);
  k_convert<<<(WTOTAL + 255) / 256, 256, 0, stream>>>(P, flag, wf);
  k_transpose<<<(TTOTAL + 255) / 256, 256, 0, stream>>>(wf);
  hipMemsetAsync(deg, 0, 20000 * sizeof(int), stream);
  k_mlp_in<<<(N_NODES + 63) / 64, 256, 0, stream>>>(d_in[0], flag, wf, h);
  k_uproj<<<N_NODES / 4, 256, 0, stream>>>(h, wf, u_s, u_d);
  k_edge_maps2<<<E_DIR / 64, 256, 0, stream>>>(u_s, u_d, ei, wf, maps, deg);
  k_scan<<<1, 256, 0, stream>>>(deg, offsets, cursor);
  k_csr_build<<<E_DIR / 256, 256, 0, stream>>>(ei, cursor, csr_eid, eslot);
  k_ftf_norm<<<(N_NODES + 255) / 256, 256, 0, stream>>>(maps, offsets, csr_eid,
                                                        Dinv, diag_n);
  k_offn2<<<E_DIR / 256, 256, 0, stream>>>(maps, ei, Dinv, eslot, csr_dst, csr_off);

  const int offW1s[2]  = {OFF_W1_0,  OFF_W1_1};
  const int offW2Ts[2] = {OFF_W2_0T, OFF_W2_1T};
  for (int l = 0; l < 2; ++l) {
    k_ht<<<N_NODES / 4, 256, 0, stream>>>(h, wf, offW1s[l], offW2Ts[l], Ht);
    k_msgs_fused<<<N_NODES / 4, 256, 0, stream>>>(offsets, csr_dst, csr_off,
                                                  diag_n, Ht, h);
  }
  k_mlp_out<<<N_NODES / 4, 256, 0, stream>>>(h, wf, flag, d_out);
}

// Round 8
// 505.698 us; speedup vs baseline: 4.5968x; 1.1334x over previous
//
#include <hip/hip_runtime.h>
#include <math.h>

#define N_NODES 20000
#define E_HALF  160000
#define E_DIR   320000
#define IN_C    512
#define HID     128
#define OUTC    40

typedef unsigned short u16;
typedef unsigned int   u32;

// f32 weight arena offsets (elements)
#define OFF_WIN1  0
#define OFF_BIN1  32768
#define OFF_WIN2  32832
#define OFF_BIN2  41024
#define OFF_WMAP1 41152
#define OFF_BMAP1 57536
#define OFF_WMAP2 57600
#define OFF_BMAP2 57856
#define OFF_WOUT1 57860
#define OFF_BOUT1 66052
#define OFF_WOUT2 66116
#define OFF_BOUT2 68676
#define OFF_W1_0  68716
#define OFF_W2_0  68720
#define OFF_W1_1  72816
#define OFF_W2_1  72820
#define WTOTAL    76916
// transposed (k-major) copies
#define OFF_W1T     76916
#define OFF_WIN2T   109684
#define OFF_WMAP1AT 117876
#define OFF_WMAP1BT 126068
#define OFF_W2_0T   134260
#define OFF_W2_1T   138356
#define OFF_WOUT1T  142452
#define TTOTAL      73728

__device__ __forceinline__ float bfu2f(u16 u) {
  union { u32 i; float f; } v; v.i = ((u32)u) << 16; return v.f;
}
__device__ __forceinline__ void unpack8(const uint4 c, float* f) {
  union { u32 i; float x; } v;
  v.i = c.x << 16;          f[0] = v.x;
  v.i = c.x & 0xffff0000u;  f[1] = v.x;
  v.i = c.y << 16;          f[2] = v.x;
  v.i = c.y & 0xffff0000u;  f[3] = v.x;
  v.i = c.z << 16;          f[4] = v.x;
  v.i = c.z & 0xffff0000u;  f[5] = v.x;
  v.i = c.w << 16;          f[6] = v.x;
  v.i = c.w & 0xffff0000u;  f[7] = v.x;
}
__device__ __forceinline__ u16 f2bf(float f) {
  union { float f; u32 u; } v; v.f = f;
  u32 u = v.u;
  u += 0x7fffu + ((u >> 16) & 1u);   // RNE
  return (u16)(u >> 16);
}

// ---- K0: sniff input float dtype. flag=1 -> bf16, flag=0 -> f32 ------------
__global__ void k_sniff(const u16* __restrict__ xv, int* __restrict__ flag) {
  __shared__ int s_bad;
  if (threadIdx.x == 0) s_bad = 0;
  __syncthreads();
  int bad = 0;
  for (int i = threadIdx.x; i < 2048; i += 256) {
    u16 u = xv[i];
    u32 ex = (u >> 7) & 0xFFu;
    if (!(ex >= 100 && ex <= 140) && (u & 0x7FFFu) != 0) bad++;
  }
  atomicAdd(&s_bad, bad);
  __syncthreads();
  if (threadIdx.x == 0) *flag = (s_bad < 64) ? 1 : 0;
}

// ---- K0b: convert all weights + build k-major transposes in one pass -------
struct P16 { const void* p[16]; };
__device__ __forceinline__ float rd_src(const void* p, int idx, int bf) {
  if (bf) return bfu2f(((const u16*)p)[idx]);
  return ((const float*)p)[idx];
}
__global__ __launch_bounds__(256) void k_convert(P16 s, const int* __restrict__ flag,
                                                 float* __restrict__ dst) {
  const int offs[17] = {OFF_WIN1, OFF_BIN1, OFF_WIN2, OFF_BIN2, OFF_WMAP1,
                        OFF_BMAP1, OFF_WMAP2, OFF_BMAP2, OFF_WOUT1, OFF_BOUT1,
                        OFF_WOUT2, OFF_BOUT2, OFF_W1_0, OFF_W2_0, OFF_W1_1,
                        OFF_W2_1, WTOTAL};
  const int i = blockIdx.x * 256 + threadIdx.x;
  const int bf = *flag;
  if (i < WTOTAL) {
    int sg = 0;
    #pragma unroll
    for (int k = 1; k < 16; ++k) if (i >= offs[k]) sg = k;
    dst[i] = rd_src(s.p[sg], i - offs[sg], bf);
    return;
  }
  const int it = i - WTOTAL;
  if (it >= TTOTAL) return;
  // {dst_off, Pidx, J, src_stride, size, colofs}
  const int tab[7][6] = {
    {OFF_W1T,      0, 64, 512, 32768,   0},
    {OFF_WIN2T,    2, 128, 64,  8192,   0},
    {OFF_WMAP1AT,  4, 64, 256,  8192,   0},
    {OFF_WMAP1BT,  4, 64, 256,  8192, 128},
    {OFF_W2_0T,   13, 64,  64,  4096,   0},
    {OFF_W2_1T,   15, 64,  64,  4096,   0},
    {OFF_WOUT1T,   8, 64, 128,  8192,   0}};
  int sg = 0, base = 0;
  #pragma unroll
  for (int t = 0; t < 7; ++t) {
    if (it >= base && it < base + tab[t][4]) { sg = t; break; }
    base += tab[t][4];
  }
  const int local = it - base;
  const int J = tab[sg][2];
  const int k = local / J, j = local - k * J;
  dst[tab[sg][0] + local] =
      rd_src(s.p[tab[sg][1]], j * tab[sg][3] + k + tab[sg][5], bf);
}

// ---- K1: h = MLP_in(x) [N,512]->relu64->[N,128]; fused u_s/u_d projection --
__global__ __launch_bounds__(256) void k_mlp_in(
    const void* __restrict__ xv, const int* __restrict__ flag,
    const float* __restrict__ wf, float* __restrict__ h,
    float* __restrict__ u_s, float* __restrict__ u_d)
{
  __shared__ float sbuf[64 * 76 + 64 * 68];   // 9216 floats
  __shared__ float s_hid[64][68];
  float (*xs)[76]  = (float(*)[76])sbuf;
  float (*wst)[68] = (float(*)[68])(sbuf + 64 * 76);
  float (*ht)[136] = (float(*)[136])sbuf;     // 64 x 136 = 8704 <= 9216

  const int t = threadIdx.x;
  const int n0 = blockIdx.x * 64;
  const int jq = t & 15, nq = t >> 4;
  const int bf = *flag;

  float4 acc[4];
  #pragma unroll
  for (int i = 0; i < 4; ++i) acc[i] = make_float4(0.f, 0.f, 0.f, 0.f);

  for (int kc = 0; kc < IN_C; kc += 64) {
    __syncthreads();
    {
      const int r0 = t >> 3, c = (t & 7) * 8;
      #pragma unroll
      for (int pp = 0; pp < 2; ++pp) {
        const int r = r0 + pp * 32;
        int node = n0 + r; if (node > N_NODES - 1) node = N_NODES - 1;
        if (bf) {
          uint4 xc = *(const uint4*)((const u16*)xv + (size_t)node * IN_C + kc + c);
          float f[8]; unpack8(xc, f);
          *(float4*)&xs[r][c]     = make_float4(f[0], f[1], f[2], f[3]);
          *(float4*)&xs[r][c + 4] = make_float4(f[4], f[5], f[6], f[7]);
        } else {
          const float* xr = (const float*)xv + (size_t)node * IN_C + kc + c;
          *(float4*)&xs[r][c]     = *(const float4*)xr;
          *(float4*)&xs[r][c + 4] = *(const float4*)(xr + 4);
        }
      }
    }
    {
      const float* src = wf + OFF_W1T + kc * 64;
      #pragma unroll
      for (int pp = 0; pp < 4; ++pp) {
        const int flat = (pp * 256 + t) * 4;
        const int k = flat >> 6, j = flat & 63;
        *(float4*)&wst[k][j] = *(const float4*)(src + flat);
      }
    }
    __syncthreads();
    #pragma unroll 4
    for (int ks = 0; ks < 64; ks += 4) {
      float4 xr[4], wr[4];
      #pragma unroll
      for (int i = 0; i < 4; ++i) xr[i] = *(float4*)&xs[nq * 4 + i][ks];
      #pragma unroll
      for (int i = 0; i < 4; ++i) wr[i] = *(float4*)&wst[ks + i][jq * 4];
      #pragma unroll
      for (int i = 0; i < 4; ++i) {
        acc[i].x += xr[i].x*wr[0].x + xr[i].y*wr[1].x + xr[i].z*wr[2].x + xr[i].w*wr[3].x;
        acc[i].y += xr[i].x*wr[0].y + xr[i].y*wr[1].y + xr[i].z*wr[2].y + xr[i].w*wr[3].y;
        acc[i].z += xr[i].x*wr[0].z + xr[i].y*wr[1].z + xr[i].z*wr[2].z + xr[i].w*wr[3].z;
        acc[i].w += xr[i].x*wr[0].w + xr[i].y*wr[1].w + xr[i].z*wr[2].w + xr[i].w*wr[3].w;
      }
    }
  }
  {
    float4 b1v = *(const float4*)(wf + OFF_BIN1 + jq * 4);
    #pragma unroll
    for (int i = 0; i < 4; ++i) {
      float4 v;
      v.x = fmaxf(acc[i].x + b1v.x, 0.f);
      v.y = fmaxf(acc[i].y + b1v.y, 0.f);
      v.z = fmaxf(acc[i].z + b1v.z, 0.f);
      v.w = fmaxf(acc[i].w + b1v.w, 0.f);
      *(float4*)&s_hid[nq * 4 + i][jq * 4] = v;
    }
  }
  __syncthreads();
  {
    #pragma unroll
    for (int pp = 0; pp < 8; ++pp) {
      const int flat = (pp * 256 + t) * 4;
      *(float4*)(sbuf + flat) = *(const float4*)(wf + OFF_WIN2T + flat);
    }
  }
  __syncthreads();
  // layer2: 8 nodes x 4 outputs per thread -> h (global) + keep for LDS tile
  float4 a2[8];
  const int o4 = t & 31, og = o4 * 4, ng = t >> 5;
  {
    #pragma unroll
    for (int i = 0; i < 8; ++i) a2[i] = make_float4(0.f, 0.f, 0.f, 0.f);
    #pragma unroll 4
    for (int k = 0; k < 64; k += 4) {
      float4 wv[4];
      #pragma unroll
      for (int i = 0; i < 4; ++i) wv[i] = *(float4*)(sbuf + (k + i) * 128 + og);
      #pragma unroll
      for (int ni = 0; ni < 8; ++ni) {
        float4 sv = *(float4*)&s_hid[ng * 8 + ni][k];
        a2[ni].x += sv.x*wv[0].x + sv.y*wv[1].x + sv.z*wv[2].x + sv.w*wv[3].x;
        a2[ni].y += sv.x*wv[0].y + sv.y*wv[1].y + sv.z*wv[2].y + sv.w*wv[3].y;
        a2[ni].z += sv.x*wv[0].z + sv.y*wv[1].z + sv.z*wv[2].z + sv.w*wv[3].z;
        a2[ni].w += sv.x*wv[0].w + sv.y*wv[1].w + sv.z*wv[2].w + sv.w*wv[3].w;
      }
    }
    float4 b2v = *(const float4*)(wf + OFF_BIN2 + og);
    #pragma unroll
    for (int ni = 0; ni < 8; ++ni) {
      a2[ni].x += b2v.x; a2[ni].y += b2v.y;
      a2[ni].z += b2v.z; a2[ni].w += b2v.w;
    }
  }
  __syncthreads();   // done reading sbuf(w2) + s_hid
  {
    #pragma unroll
    for (int ni = 0; ni < 8; ++ni) {
      const int node = n0 + ng * 8 + ni;
      *(float4*)&ht[ng * 8 + ni][og] = a2[ni];
      if (node < N_NODES) *(float4*)&h[(size_t)node * HID + og] = a2[ni];
    }
  }
  __syncthreads();
  // fused u-projection: u_s = ht @ W1a^T, u_d = ht @ W1b^T (128 -> 64 each)
  #pragma unroll
  for (int half = 0; half < 2; ++half) {
    const float* wsrc = wf + (half == 0 ? OFF_WMAP1AT : OFF_WMAP1BT);
    float* uout = (half == 0) ? u_s : u_d;
    float4 ua[4];
    #pragma unroll
    for (int i = 0; i < 4; ++i) ua[i] = make_float4(0.f, 0.f, 0.f, 0.f);
    for (int ks = 0; ks < 128; ks += 4) {
      float4 xr[4], wr[4];
      #pragma unroll
      for (int i = 0; i < 4; ++i) xr[i] = *(float4*)&ht[nq * 4 + i][ks];
      #pragma unroll
      for (int i = 0; i < 4; ++i) wr[i] = *(const float4*)(wsrc + (ks + i) * 64 + jq * 4);
      #pragma unroll
      for (int i = 0; i < 4; ++i) {
        ua[i].x += xr[i].x*wr[0].x + xr[i].y*wr[1].x + xr[i].z*wr[2].x + xr[i].w*wr[3].x;
        ua[i].y += xr[i].x*wr[0].y + xr[i].y*wr[1].y + xr[i].z*wr[2].y + xr[i].w*wr[3].y;
        ua[i].z += xr[i].x*wr[0].z + xr[i].y*wr[1].z + xr[i].z*wr[2].z + xr[i].w*wr[3].z;
        ua[i].w += xr[i].x*wr[0].w + xr[i].y*wr[1].w + xr[i].z*wr[2].w + xr[i].w*wr[3].w;
      }
    }
    #pragma unroll
    for (int i = 0; i < 4; ++i) {
      const int node = n0 + nq * 4 + i;
      if (node < N_NODES) *(float4*)&uout[(size_t)node * 64 + jq * 4] = ua[i];
    }
  }
}

// ---- K2: edge maps from node projections; deg histogram fused --------------
__global__ __launch_bounds__(256) void k_edge_maps2(
    const float* __restrict__ u_s, const float* __restrict__ u_d,
    const int* __restrict__ ei, const float* __restrict__ wf,
    float* __restrict__ maps, int* __restrict__ deg)
{
  __shared__ float s_act[64][68];
  const int t = threadIdx.x;
  const int w = t >> 6, l = t & 63;
  const int e0 = blockIdx.x * 64;
  const float bias = wf[OFF_BMAP1 + l];
  const int eb = e0 + w * 16;
  if (l < 16) atomicAdd(&deg[ei[eb + l]], 1);
  #pragma unroll 4
  for (int i = 0; i < 16; ++i) {
    const int e = eb + i;
    const int sn = ei[e], dn = ei[E_DIR + e];
    float v = u_s[sn * 64 + l] + u_d[dn * 64 + l] + bias;
    s_act[w * 16 + i][l] = fmaxf(v, 0.f);
  }
  __syncthreads();
  const int ee = t >> 2, ko = t & 3;
  float acc = wf[OFF_BMAP2 + ko];
  const float* wr = wf + OFF_WMAP2 + ko * 64;
  #pragma unroll
  for (int j = 0; j < 64; j += 4) {
    float4 wv = *(const float4*)(wr + j);
    float4 av = *(const float4*)(&s_act[ee][j]);
    acc += av.x*wv.x + av.y*wv.y + av.z*wv.z + av.w*wv.w;
  }
  maps[(e0 + ee) * 4 + ko] = acc;
}

// ---- K4b: exclusive scan of deg -> offsets (+cursor copy), 1 block ---------
__global__ __launch_bounds__(256) void k_scan(
    const int* __restrict__ deg, int* __restrict__ offsets,
    int* __restrict__ cursor)
{
  __shared__ int s[256];
  const int t = threadIdx.x;
  const int c0 = t * 79;
  int sum = 0;
  for (int i = 0; i < 79; ++i) {
    int idx = c0 + i;
    if (idx < N_NODES) sum += deg[idx];
  }
  s[t] = sum;
  __syncthreads();
  int run = sum;
  for (int off = 1; off < 256; off <<= 1) {
    int tmp = (t >= off) ? s[t - off] : 0;
    __syncthreads();
    s[t] += tmp;
    __syncthreads();
  }
  int base = s[t] - run;
  for (int i = 0; i < 79; ++i) {
    int idx = c0 + i;
    if (idx < N_NODES) {
      offsets[idx] = base;
      cursor[idx] = base;
      base += deg[idx];
    }
  }
  if (t == 255) offsets[N_NODES] = E_DIR;
}

// ---- K4c: bucket edges by src; record slot of each edge --------------------
__global__ __launch_bounds__(256) void k_csr_build(
    const int* __restrict__ ei, int* __restrict__ cursor,
    int* __restrict__ csr_eid, int* __restrict__ eslot)
{
  const int e = blockIdx.x * 256 + threadIdx.x;
  if (e >= E_DIR) return;
  const int sn = ei[e];
  const int pos = atomicAdd(&cursor[sn], 1);
  csr_eid[pos] = e;
  eslot[e] = pos;
}

// ---- K4d: per-node FtF gather + 2x2 eig -> Dinv, diag_n (no atomics) -------
__global__ __launch_bounds__(256) void k_ftf_norm(
    const float* __restrict__ maps, const int* __restrict__ offsets,
    const int* __restrict__ csr_eid, float* __restrict__ Dinv,
    float* __restrict__ diag_n)
{
  const int n = blockIdx.x * 256 + threadIdx.x;
  if (n >= N_NODES) return;
  const int s = offsets[n], e = offsets[n + 1];
  float a = 0.f, b = 0.f, c = 0.f;
  for (int p = s; p < e; ++p) {
    const int eid = csr_eid[p];
    float4 m = *(const float4*)(maps + (size_t)eid * 4);
    a += m.x * m.x + m.z * m.z;
    b += m.x * m.y + m.z * m.w;
    c += m.y * m.y + m.w * m.w;
  }
  float mean = 0.5f * (a + c), diff = 0.5f * (a - c);
  float rad = sqrtf(diff * diff + b * b);
  float l1 = mean - rad, l2 = mean + rad;
  float s1 = 1.0f / sqrtf(fmaxf(l1, 1e-6f));
  float s2 = 1.0f / sqrtf(fmaxf(l2, 1e-6f));
  float D00, D01, D11;
  if (rad < 1e-20f) {
    float s0 = 1.0f / sqrtf(fmaxf(mean, 1e-6f));
    D00 = s0; D01 = 0.f; D11 = s0;
  } else {
    float vx, vy;
    if (diff >= 0.f) { vx = rad + diff; vy = b; }
    else             { vx = b;          vy = rad - diff; }
    float inv = 1.0f / sqrtf(vx * vx + vy * vy);
    float ux = vx * inv, uy = vy * inv;
    D00 = s1 * uy * uy + s2 * ux * ux;
    D01 = (s2 - s1) * ux * uy;
    D11 = s1 * ux * ux + s2 * uy * uy;
  }
  Dinv[n * 4 + 0] = D00; Dinv[n * 4 + 1] = D01;
  Dinv[n * 4 + 2] = D01; Dinv[n * 4 + 3] = D11;
  float t00 = D00 * a + D01 * b, t01 = D00 * b + D01 * c;
  float t10 = D01 * a + D11 * b, t11 = D01 * b + D11 * c;
  diag_n[n * 4 + 0] = t00 * D00 + t01 * D01;
  diag_n[n * 4 + 1] = t00 * D01 + t01 * D11;
  diag_n[n * 4 + 2] = t10 * D00 + t11 * D01;
  diag_n[n * 4 + 3] = t10 * D01 + t11 * D11;
}

// ---- K5: off_n into CSR slots via eslot (no atomics) -----------------------
__global__ void k_offn2(const float* __restrict__ maps, const int* __restrict__ ei,
                        const float* __restrict__ Dinv, const int* __restrict__ eslot,
                        int* __restrict__ csr_dst, float4* __restrict__ csr_off)
{
  const int e = blockIdx.x * 256 + threadIdx.x;
  if (e >= E_DIR) return;
  const int r = (e < E_HALF) ? (e + E_HALF) : (e - E_HALF);
  float4 me = *(const float4*)(maps + (size_t)e * 4);
  float4 mr = *(const float4*)(maps + (size_t)r * 4);
  float o00 = -(me.x * mr.x + me.z * mr.z);
  float o01 = -(me.x * mr.y + me.z * mr.w);
  float o10 = -(me.y * mr.x + me.w * mr.z);
  float o11 = -(me.y * mr.y + me.w * mr.w);
  const int sn = ei[e], dn = ei[E_DIR + e];
  float4 Ds = *(const float4*)(Dinv + sn * 4);
  float4 Dd = *(const float4*)(Dinv + dn * 4);
  float t00 = Ds.x * o00 + Ds.y * o10;
  float t01 = Ds.x * o01 + Ds.y * o11;
  float t10 = Ds.z * o00 + Ds.w * o10;
  float t11 = Ds.z * o01 + Ds.w * o11;
  float4 q;
  q.x = t00 * Dd.x + t01 * Dd.z;
  q.y = t00 * Dd.y + t01 * Dd.w;
  q.z = t10 * Dd.x + t11 * Dd.z;
  q.w = t10 * Dd.y + t11 * Dd.w;
  const int pos = eslot[e];
  csr_dst[pos] = dn;
  csr_off[pos] = q;
}

// ---- K6a: Ht = W1^T (h3 @ W2^T) per node -----------------------------------
__global__ __launch_bounds__(256) void k_ht(
    const float* __restrict__ h, const float* __restrict__ wf,
    int offW1, int offW2T, float* __restrict__ Ht)
{
  const int t = threadIdx.x;
  const int n = blockIdx.x * 4 + (t >> 6);
  const int g = t & 63;
  const float w1_00 = wf[offW1 + 0], w1_01 = wf[offW1 + 1];
  const float w1_10 = wf[offW1 + 2], w1_11 = wf[offW1 + 3];
  float acc0 = 0.f, acc1 = 0.f;
  const float* wt = wf + offW2T + g;
  const float* h0 = h + (size_t)n * HID;
  #pragma unroll 4
  for (int kk = 0; kk < 64; kk += 4) {
    float4 p0 = *(const float4*)(h0 + kk);
    float4 p1 = *(const float4*)(h0 + 64 + kk);
    const float* w0 = wt + kk * 64;
    float wv0 = w0[0], wv1 = w0[64], wv2 = w0[128], wv3 = w0[192];
    acc0 += p0.x*wv0 + p0.y*wv1 + p0.z*wv2 + p0.w*wv3;
    acc1 += p1.x*wv0 + p1.y*wv1 + p1.z*wv2 + p1.w*wv3;
  }
  Ht[n * HID + g]      = w1_00 * acc0 + w1_10 * acc1;
  Ht[n * HID + 64 + g] = w1_01 * acc0 + w1_11 * acc1;
}

// ---- K6b: per-node gather msgs + diag term + ELU + h update (fused) --------
__global__ __launch_bounds__(256) void k_msgs_fused(
    const int* __restrict__ offsets, const int* __restrict__ csr_dst,
    const float4* __restrict__ csr_off, const float* __restrict__ diag_n,
    const float* __restrict__ Ht, float* __restrict__ h)
{
  const int n = blockIdx.x * 4 + (threadIdx.x >> 6);
  const int g = threadIdx.x & 63;
  const int s = offsets[n], e = offsets[n + 1];
  float acc0 = 0.f, acc1 = 0.f;
  int d_next = (s < e) ? csr_dst[s] : 0;
  float4 o_next = (s < e) ? csr_off[s] : make_float4(0.f, 0.f, 0.f, 0.f);
  for (int k = s; k < e; ++k) {
    const int d = d_next;
    const float4 o = o_next;
    if (k + 1 < e) { d_next = csr_dst[k + 1]; o_next = csr_off[k + 1]; }
    const float ht0 = Ht[(size_t)d * HID + g];
    const float ht1 = Ht[(size_t)d * HID + 64 + g];
    acc0 += o.x * ht0 + o.y * ht1;
    acc1 += o.z * ht0 + o.w * ht1;
  }
  const float4 dn = *(const float4*)(diag_n + n * 4);
  const float ht0 = Ht[(size_t)n * HID + g];
  const float ht1 = Ht[(size_t)n * HID + 64 + g];
  float lh0 = dn.x * ht0 + dn.y * ht1 + acc0;
  float lh1 = dn.z * ht0 + dn.w * ht1 + acc1;
  lh0 = (lh0 > 0.f) ? lh0 : (expf(lh0) - 1.f);
  lh1 = (lh1 > 0.f) ? lh1 : (expf(lh1) - 1.f);
  h[(size_t)n * HID + g]      -= lh0;
  h[(size_t)n * HID + 64 + g] -= lh1;
}

// ---- K7: out = MLP_out(h) [N,128]->relu64->40, LDS-tiled 64 nodes/block ----
__global__ __launch_bounds__(256) void k_mlp_out2(
    const float* __restrict__ h, const float* __restrict__ wf,
    const int* __restrict__ flag, void* __restrict__ outv)
{
  __shared__ float ht[64][132];   // 128-wide tile + pad (stride must be >=128!)
  __shared__ float s_hid[64][68];
  const int t = threadIdx.x;
  const int n0 = blockIdx.x * 64;
  // stage h tile (64 x 128), coalesced
  {
    #pragma unroll
    for (int pp = 0; pp < 8; ++pp) {
      const int flat = pp * 256 + t;           // 2048 float4 slots
      const int r = flat >> 5, c = (flat & 31) * 4;
      int node = n0 + r; if (node > N_NODES - 1) node = N_NODES - 1;
      *(float4*)&ht[r][c] = *(const float4*)(h + (size_t)node * HID + c);
    }
  }
  __syncthreads();
  // layer1: 4 nodes x 4 j per thread, k-major weights from global (L1)
  {
    const int jq = t & 15, nq = t >> 4;
    float4 acc[4];
    #pragma unroll
    for (int i = 0; i < 4; ++i) acc[i] = make_float4(0.f, 0.f, 0.f, 0.f);
    for (int ks = 0; ks < 128; ks += 4) {
      float4 xr[4], wr[4];
      #pragma unroll
      for (int i = 0; i < 4; ++i) xr[i] = *(float4*)&ht[nq * 4 + i][ks];
      #pragma unroll
      for (int i = 0; i < 4; ++i)
        wr[i] = *(const float4*)(wf + OFF_WOUT1T + (ks + i) * 64 + jq * 4);
      #pragma unroll
      for (int i = 0; i < 4; ++i) {
        acc[i].x += xr[i].x*wr[0].x + xr[i].y*wr[1].x + xr[i].z*wr[2].x + xr[i].w*wr[3].x;
        acc[i].y += xr[i].x*wr[0].y + xr[i].y*wr[1].y + xr[i].z*wr[2].y + xr[i].w*wr[3].y;
        acc[i].z += xr[i].x*wr[0].z + xr[i].y*wr[1].z + xr[i].z*wr[2].z + xr[i].w*wr[3].z;
        acc[i].w += xr[i].x*wr[0].w + xr[i].y*wr[1].w + xr[i].z*wr[2].w + xr[i].w*wr[3].w;
      }
    }
    float4 b1v = *(const float4*)(wf + OFF_BOUT1 + jq * 4);
    #pragma unroll
    for (int i = 0; i < 4; ++i) {
      float4 v;
      v.x = fmaxf(acc[i].x + b1v.x, 0.f);
      v.y = fmaxf(acc[i].y + b1v.y, 0.f);
      v.z = fmaxf(acc[i].z + b1v.z, 0.f);
      v.w = fmaxf(acc[i].w + b1v.w, 0.f);
      *(float4*)&s_hid[nq * 4 + i][jq * 4] = v;
    }
  }
  __syncthreads();
  // layer2: 2560 outputs (64 nodes x 40), 10 per thread
  const int bf = *flag;
  #pragma unroll
  for (int pp = 0; pp < 10; ++pp) {
    const int flat = pp * 256 + t;
    const int nl = flat / 40, o = flat - nl * 40;
    float acc = wf[OFF_BOUT2 + o];
    const float* wr = wf + OFF_WOUT2 + o * 64;
    #pragma unroll
    for (int j = 0; j < 64; j += 4) {
      float4 wv = *(const float4*)(wr + j);
      acc += s_hid[nl][j]*wv.x + s_hid[nl][j+1]*wv.y
           + s_hid[nl][j+2]*wv.z + s_hid[nl][j+3]*wv.w;
    }
    const int node = n0 + nl;
    if (node < N_NODES) {
      const int idx = node * OUTC + o;
      if (bf) ((u16*)outv)[idx] = f2bf(acc);
      else    ((float*)outv)[idx] = acc;
    }
  }
}

extern "C" void kernel_launch(void* const* d_in, const int* in_sizes, int n_in,
                              void* d_out, int out_size, void* d_ws, size_t ws_size,
                              hipStream_t stream)
{
  const int* ei = (const int*)d_in[1];

  float* ws   = (float*)d_ws;
  float* wf   = ws;                               // [0, 150644) incl. transposes
  int*   flag = (int*)(ws + 150656);
  float* h      = ws + 150672;                    // 2,560,000
  float* Ht     = h + 2560000;                    // 2,560,000
  float* csr_offv = Ht + 2560000;                 // 1,280,000 (float4[E_DIR])
  float* Dinv   = csr_offv + 1280000;             // 80,000
  float* diag_n = Dinv + 80000;                   // 80,000
  float* X      = diag_n + 80000;                 // maps + CSR index arrays
  float* maps   = X;                              // 1,280,000 floats
  int*   csr_dst = (int*)(X + 1280000);           // 320,000
  int*   csr_eid = (int*)(X + 1600000);           // 320,000
  int*   eslot   = (int*)(X + 1920000);           // 320,000
  int*   offsets = (int*)(X + 2240000);           // 20,001
  int*   cursor  = (int*)(X + 2260002);           // 20,000
  int*   deg     = (int*)(X + 2280002);           // 20,000
  float* u_s    = Ht;                             // alias (dead until k_ht)
  float* u_d    = Ht + 1280000;
  float4* csr_off = (float4*)csr_offv;

  P16 P;
  for (int i = 0; i < 16; ++i) P.p[i] = d_in[2 + i];

  k_sniff<<<1, 256, 0, stream>>>((const u16*)d_in[0], flag);
  k_convert<<<(WTOTAL + TTOTAL + 255) / 256, 256, 0, stream>>>(P, flag, wf);
  hipMemsetAsync(deg, 0, 20000 * sizeof(int), stream);
  k_mlp_in<<<(N_NODES + 63) / 64, 256, 0, stream>>>(d_in[0], flag, wf, h, u_s, u_d);
  k_edge_maps2<<<E_DIR / 64, 256, 0, stream>>>(u_s, u_d, ei, wf, maps, deg);
  k_scan<<<1, 256, 0, stream>>>(deg, offsets, cursor);
  k_csr_build<<<E_DIR / 256, 256, 0, stream>>>(ei, cursor, csr_eid, eslot);
  k_ftf_norm<<<(N_NODES + 255) / 256, 256, 0, stream>>>(maps, offsets, csr_eid,
                                                        Dinv, diag_n);
  k_offn2<<<E_DIR / 256, 256, 0, stream>>>(maps, ei, Dinv, eslot, csr_dst, csr_off);

  const int offW1s[2]  = {OFF_W1_0,  OFF_W1_1};
  const int offW2Ts[2] = {OFF_W2_0T, OFF_W2_1T};
  for (int l = 0; l < 2; ++l) {
    k_ht<<<N_NODES / 4, 256, 0, stream>>>(h, wf, offW1s[l], offW2Ts[l], Ht);
    k_msgs_fused<<<N_NODES / 4, 256, 0, stream>>>(offsets, csr_dst, csr_off,
                                                  diag_n, Ht, h);
  }
  k_mlp_out2<<<(N_NODES + 63) / 64, 256, 0, stream>>>(h, wf, flag, d_out);
}